// Round 1
// baseline (397.654 us; speedup 1.0000x reference)
//
#include <hip/hip_runtime.h>
#include <math.h>

#define N_NODES 50000
#define N_EDGES 1600000

// ---------- complex 2x2 helpers ----------
struct C2 { float x, y; };
__device__ inline C2 mkc(float x, float y){ C2 r; r.x=x; r.y=y; return r; }
__device__ inline C2 cmul(C2 a, C2 b){ return mkc(a.x*b.x - a.y*b.y, a.x*b.y + a.y*b.x); }
__device__ inline C2 cadd(C2 a, C2 b){ return mkc(a.x+b.x, a.y+b.y); }

// ---------- K1: per-pair observable B = A^dag Z A, folded into feature coeffs ----------
// feature_p = c0 + (c1*rawS0_a + c2*rawX_a)/rawT
// c0 = 0.5+0.5*B11, c1 = 0.5*(B00-B11), c2 = Re(B01)
__global__ void k_pairs(const float* __restrict__ qw, float4* __restrict__ cmat){
    int p = blockIdx.x*blockDim.x + threadIdx.x;
    if (p >= 28) return;
    int a = 0; { int rem = p, q = 0; while (rem >= 7 - q){ rem -= 7 - q; q++; } a = q; }
    C2 M00 = mkc(1,0), M01 = mkc(0,0), M10 = mkc(0,0), M11 = mkc(1,0);
    for (int k = 0; k < 6; k++){
        float th = 0.5f * qw[p*6 + k];
        float s, c; sincosf(th, &s, &c);
        C2 R00, R01, R10, R11;
        int type = k % 3;
        if (type == 0){      // Rx: [[c,-is],[-is,c]]
            R00 = mkc(c,0); R01 = mkc(0,-s); R10 = mkc(0,-s); R11 = mkc(c,0);
        } else if (type == 1){ // Ry: [[c,-s],[s,c]]
            R00 = mkc(c,0); R01 = mkc(-s,0); R10 = mkc(s,0); R11 = mkc(c,0);
        } else {             // Rz: diag(c-is, c+is)
            R00 = mkc(c,-s); R01 = mkc(0,0); R10 = mkc(0,0); R11 = mkc(c,s);
        }
        C2 N00 = cadd(cmul(R00,M00), cmul(R01,M10));
        C2 N01 = cadd(cmul(R00,M01), cmul(R01,M11));
        C2 N10 = cadd(cmul(R10,M00), cmul(R11,M10));
        C2 N11 = cadd(cmul(R10,M01), cmul(R11,M11));
        M00=N00; M01=N01; M10=N10; M11=N11;
    }
    float B00  = (M00.x*M00.x + M00.y*M00.y) - (M10.x*M10.x + M10.y*M10.y);
    float B11  = (M01.x*M01.x + M01.y*M01.y) - (M11.x*M11.x + M11.y*M11.y);
    float B01r = (M00.x*M01.x + M00.y*M01.y) - (M10.x*M11.x + M10.y*M11.y);
    cmat[p] = make_float4(0.5f + 0.5f*B11, 0.5f*(B00 - B11), B01r, (float)a);
}

// ---------- edge dtype probe: int64 vs int32 (jax default demotes to int32) ----------
__global__ void k_probe(const void* __restrict__ ei, int* __restrict__ flag){
    if (threadIdx.x == 0 && blockIdx.x == 0){
        const long long* e64 = (const long long*)ei;
        int ok = 1;
        for (int i = 0; i < 64; i++){
            long long v = e64[i];
            if (v < 0 || v >= N_NODES) ok = 0;
        }
        flag[0] = ok;
    }
}

__device__ inline int get_edge(const void* ei, int is64, long long idx){
    if (is64) return (int)((const long long*)ei)[idx];
    return ((const int*)ei)[idx];
}

// ---------- degree histogram over dst ----------
__global__ __launch_bounds__(256) void k_hist(const void* __restrict__ ei,
        const int* __restrict__ flag, int* __restrict__ deg){
    int e = blockIdx.x*256 + threadIdx.x;
    if (e >= N_EDGES) return;
    int is64 = flag[0];
    int dst = get_edge(ei, is64, (long long)N_EDGES + e);
    atomicAdd(&deg[dst], 1);
}

__global__ __launch_bounds__(256) void k_dinv(const int* __restrict__ deg, float* __restrict__ dinv){
    int n = blockIdx.x*256 + threadIdx.x;
    if (n < N_NODES) dinv[n] = rsqrtf((float)(deg[n] + 1)); // +1 self loop
}

// ---------- quantum features: one wave per node ----------
// lane holds float4 x[4l..4l+3]; flat-bit j of index <-> qubit 7-j.
// register bits: bit0 <-> qubit7 (unused), bit1 <-> qubit6; lane bit j <-> qubit 5-j.
__global__ __launch_bounds__(256) void k_feat(const float* __restrict__ x,
        const float* __restrict__ dinv, const float4* __restrict__ cmat,
        float* __restrict__ z){
    int wave = threadIdx.x >> 6;
    int lane = threadIdx.x & 63;
    int n = blockIdx.x*4 + wave;
    const float4 v = ((const float4*)(x + (size_t)n*256))[lane];
    float persq = v.x*v.x + v.y*v.y + v.z*v.z + v.w*v.w;

    float red[15];
    red[0] = persq;                    // T
    red[1] = v.x*v.x + v.y*v.y;        // S0 qubit6 (elements 0,1 have reg-bit1 = 0)
    red[2] = v.x*v.z + v.y*v.w;        // X qubit6
    #pragma unroll
    for (int j = 0; j < 6; j++){
        float4 pv;
        pv.x = __shfl_xor(v.x, 1 << j);
        pv.y = __shfl_xor(v.y, 1 << j);
        pv.z = __shfl_xor(v.z, 1 << j);
        pv.w = __shfl_xor(v.w, 1 << j);
        red[3 + j] = v.x*pv.x + v.y*pv.y + v.z*pv.z + v.w*pv.w; // 2*X (qubit 5-j)
        red[9 + j] = ((lane >> j) & 1) ? 0.0f : persq;          // S0 (qubit 5-j)
    }
    #pragma unroll
    for (int m = 1; m < 64; m <<= 1){
        #pragma unroll
        for (int k = 0; k < 15; k++) red[k] += __shfl_xor(red[k], m);
    }
    // lane q (q<7) holds S0_q / X_q for the shfl-gather below
    float s0_by_lane =
        lane == 0 ? red[14] : lane == 1 ? red[13] : lane == 2 ? red[12] :
        lane == 3 ? red[11] : lane == 4 ? red[10] : lane == 5 ? red[9]  : red[1];
    float x_by_lane =
        lane == 0 ? 0.5f*red[8] : lane == 1 ? 0.5f*red[7] : lane == 2 ? 0.5f*red[6] :
        lane == 3 ? 0.5f*red[5] : lane == 4 ? 0.5f*red[4] : lane == 5 ? 0.5f*red[3] : red[2];

    float4 cm = cmat[lane < 28 ? lane : 0];
    int ap = (int)cm.w;
    float S0a = __shfl(s0_by_lane, ap);
    float Xa  = __shfl(x_by_lane,  ap);
    float invT = 1.0f / red[0];
    float feat = cm.x + (cm.y*S0a + cm.z*Xa) * invT;
    if (lane < 28) z[(size_t)n*28 + lane] = dinv[n] * feat;
}

// ---------- exclusive scan of deg (3 kernels, 256-wide blocks) ----------
__global__ __launch_bounds__(256) void k_scan1(const int* __restrict__ deg,
        int* __restrict__ part, int* __restrict__ bsums){
    __shared__ int sh[256];
    int tid = threadIdx.x, gid = blockIdx.x*256 + tid;
    int v = (gid < N_NODES) ? deg[gid] : 0;
    sh[tid] = v; __syncthreads();
    for (int ofs = 1; ofs < 256; ofs <<= 1){
        int t = (tid >= ofs) ? sh[tid - ofs] : 0; __syncthreads();
        sh[tid] += t; __syncthreads();
    }
    if (gid < N_NODES) part[gid] = sh[tid] - v; // exclusive
    if (tid == 255) bsums[blockIdx.x] = sh[255];
}

__global__ __launch_bounds__(256) void k_scan2(const int* __restrict__ bsums,
        int* __restrict__ bofs, int nb){
    __shared__ int sh[256];
    int tid = threadIdx.x;
    int v = (tid < nb) ? bsums[tid] : 0;
    sh[tid] = v; __syncthreads();
    for (int ofs = 1; ofs < 256; ofs <<= 1){
        int t = (tid >= ofs) ? sh[tid - ofs] : 0; __syncthreads();
        sh[tid] += t; __syncthreads();
    }
    if (tid < nb) bofs[tid] = sh[tid] - v;
}

__global__ __launch_bounds__(256) void k_scan3(const int* __restrict__ part,
        const int* __restrict__ bofs, int* __restrict__ offs){
    int gid = blockIdx.x*256 + threadIdx.x;
    if (gid < N_NODES) offs[gid] = part[gid] + bofs[blockIdx.x];
}

// ---------- CSR build (counting sort by dst) ----------
__global__ __launch_bounds__(256) void k_csr(const void* __restrict__ ei,
        const int* __restrict__ flag, const int* __restrict__ offs,
        int* __restrict__ cnt, int* __restrict__ csr){
    int e = blockIdx.x*256 + threadIdx.x;
    if (e >= N_EDGES) return;
    int is64 = flag[0];
    int src = get_edge(ei, is64, e);
    int dst = get_edge(ei, is64, (long long)N_EDGES + e);
    int pos = offs[dst] + atomicAdd(&cnt[dst], 1);
    csr[pos] = src;
}

// ---------- GCN aggregate + relu: out[n] = relu(dinv[n]*(z[n] + sum z[src])) ----------
__device__ inline void f4acc(float4& a, const float4 b){ a.x+=b.x; a.y+=b.y; a.z+=b.z; a.w+=b.w; }

__global__ __launch_bounds__(256) void k_gather(const float* __restrict__ z,
        const float* __restrict__ dinv, const int* __restrict__ deg,
        const int* __restrict__ offs, const int* __restrict__ csr,
        float* __restrict__ out){
    int n = blockIdx.x*256 + threadIdx.x;
    if (n >= N_NODES) return;
    const float4* self = (const float4*)(z + (size_t)n*28);
    float4 A[7];
    #pragma unroll
    for (int q = 0; q < 7; q++) A[q] = self[q];
    int dn = deg[n], off = offs[n];
    for (int e = 0; e < dn; e++){
        int s = csr[off + e];
        const float4* r = (const float4*)(z + (size_t)s*28);
        #pragma unroll
        for (int q = 0; q < 7; q++) f4acc(A[q], r[q]);
    }
    float dv = dinv[n];
    float4* o = (float4*)(out + (size_t)n*28);
    #pragma unroll
    for (int q = 0; q < 7; q++)
        o[q] = make_float4(fmaxf(A[q].x*dv, 0.f), fmaxf(A[q].y*dv, 0.f),
                           fmaxf(A[q].z*dv, 0.f), fmaxf(A[q].w*dv, 0.f));
}

// ---------- Gram: G[i*28+j] = sum_n out[n,i]*out[n,j] ----------
__global__ __launch_bounds__(256) void k_gram(const float* __restrict__ out, float* __restrict__ G){
    __shared__ float buf[64*28];
    int tid = threadIdx.x;
    int e[4]; int ii[4], jj[4]; bool val[4];
    #pragma unroll
    for (int k = 0; k < 4; k++){
        e[k] = tid + 256*k;
        val[k] = e[k] < 784;
        int ee = val[k] ? e[k] : 0;
        ii[k] = ee / 28; jj[k] = ee - 28*ii[k];
    }
    float acc[4] = {0.f, 0.f, 0.f, 0.f};
    int nchunks = (N_NODES + 63) / 64;
    for (int ch = blockIdx.x; ch < nchunks; ch += gridDim.x){
        int base = ch * 64;
        int total = (N_NODES - base < 64 ? N_NODES - base : 64) * 28;
        __syncthreads();
        for (int t = tid; t < 64*28; t += 256)
            buf[t] = (t < total) ? out[(size_t)base*28 + t] : 0.f;
        __syncthreads();
        for (int n = 0; n < 64; n++){
            const float* r = buf + n*28;
            #pragma unroll
            for (int k = 0; k < 4; k++) acc[k] += r[ii[k]] * r[jj[k]];
        }
    }
    #pragma unroll
    for (int k = 0; k < 4; k++) if (val[k]) atomicAdd(&G[e[k]], acc[k]);
}

// ---------- MLP ----------
__global__ __launch_bounds__(256) void k_mlp1(const float* __restrict__ G,
        const float* __restrict__ W1, const float* __restrict__ b1, float* __restrict__ h){
    int j = blockIdx.x;
    const float* w = W1 + (size_t)j*784;
    float s = 0.f;
    for (int i = threadIdx.x; i < 784; i += 256) s += G[i] * w[i];
    __shared__ float sh[256];
    sh[threadIdx.x] = s; __syncthreads();
    for (int ofs = 128; ofs > 0; ofs >>= 1){
        if (threadIdx.x < ofs) sh[threadIdx.x] += sh[threadIdx.x + ofs];
        __syncthreads();
    }
    if (threadIdx.x == 0) h[j] = fmaxf(sh[0] + b1[j], 0.f);
}

__global__ void k_mlp2(const float* __restrict__ h, const float* __restrict__ W2,
        const float* __restrict__ b2, float* __restrict__ outp){
    __shared__ float sh[128];
    int t = threadIdx.x;
    sh[t] = h[t] * W2[t];
    __syncthreads();
    for (int ofs = 64; ofs > 0; ofs >>= 1){
        if (t < ofs) sh[t] += sh[t + ofs];
        __syncthreads();
    }
    if (t == 0) outp[0] = 1.f / (1.f + expf(-(sh[0] + b2[0])));
}

extern "C" void kernel_launch(void* const* d_in, const int* in_sizes, int n_in,
                              void* d_out, int out_size, void* d_ws, size_t ws_size,
                              hipStream_t stream){
    const float* x  = (const float*)d_in[0];
    const void*  ei = d_in[1];
    const float* qw = (const float*)d_in[2];
    const float* W1 = (const float*)d_in[3];
    const float* b1 = (const float*)d_in[4];
    const float* W2 = (const float*)d_in[5];
    const float* b2 = (const float*)d_in[6];
    float* outp = (float*)d_out;

    char* base = (char*)d_ws;
    float*  z    = (float*)base;  base += (size_t)N_NODES*28*4;
    float*  ob   = (float*)base;  base += (size_t)N_NODES*28*4;
    int*    csr  = (int*)base;    base += (size_t)N_EDGES*4;
    int*    deg  = (int*)base;    base += (size_t)N_NODES*4;
    float*  dinv = (float*)base;  base += (size_t)N_NODES*4;
    int*    offs = (int*)base;    base += (size_t)N_NODES*4;
    int*    cnt  = (int*)base;    base += (size_t)N_NODES*4;
    int*    part = (int*)base;    base += (size_t)N_NODES*4;
    int*    bsums= (int*)base;    base += 1024;
    int*    bofs = (int*)base;    base += 1024;
    float4* cmat = (float4*)base; base += 448;
    float*  G    = (float*)base;  base += 784*4;
    float*  h    = (float*)base;  base += 512;
    int*    flag = (int*)base;    base += 16;

    hipMemsetAsync(deg, 0, (size_t)N_NODES*4, stream);
    hipMemsetAsync(cnt, 0, (size_t)N_NODES*4, stream);
    hipMemsetAsync(G,   0, 784*4, stream);

    int nbN = (N_NODES + 255) / 256;   // 196
    int nbE = (N_EDGES + 255) / 256;   // 6250

    k_probe<<<1, 64, 0, stream>>>(ei, flag);
    k_pairs<<<1, 32, 0, stream>>>(qw, cmat);
    k_hist<<<nbE, 256, 0, stream>>>(ei, flag, deg);
    k_dinv<<<nbN, 256, 0, stream>>>(deg, dinv);
    k_feat<<<N_NODES/4, 256, 0, stream>>>(x, dinv, cmat, z);
    k_scan1<<<nbN, 256, 0, stream>>>(deg, part, bsums);
    k_scan2<<<1, 256, 0, stream>>>(bsums, bofs, nbN);
    k_scan3<<<nbN, 256, 0, stream>>>(part, bofs, offs);
    k_csr<<<nbE, 256, 0, stream>>>(ei, flag, offs, cnt, csr);
    k_gather<<<nbN, 256, 0, stream>>>(z, dinv, deg, offs, csr, ob);
    k_gram<<<196, 256, 0, stream>>>(ob, G);
    k_mlp1<<<128, 256, 0, stream>>>(G, W1, b1, h);
    k_mlp2<<<1, 128, 0, stream>>>(h, W2, b2, outp);
}

// Round 2
// 343.720 us; speedup vs baseline: 1.1569x; 1.1569x over previous
//
#include <hip/hip_runtime.h>
#include <math.h>

#define N_NODES 50000
#define N_EDGES 1600000
#define NB_BUCKETS 391      // ceil(50000/128), bucket = dst>>7
#define PART_CHUNK 8192
#define GS_CAP 6144         // mean bucket size 4096, sigma 64 -> 6144 is ~32 sigma

// ---------- complex 2x2 helpers ----------
struct C2 { float x, y; };
__device__ inline C2 mkc(float x, float y){ C2 r; r.x=x; r.y=y; return r; }
__device__ inline C2 cmul(C2 a, C2 b){ return mkc(a.x*b.x - a.y*b.y, a.x*b.y + a.y*b.x); }
__device__ inline C2 cadd(C2 a, C2 b){ return mkc(a.x+b.x, a.y+b.y); }

// ---------- K1: per-pair observable B = A^dag Z A, folded into feature coeffs ----------
__global__ void k_pairs(const float* __restrict__ qw, float4* __restrict__ cmat){
    int p = blockIdx.x*blockDim.x + threadIdx.x;
    if (p >= 28) return;
    int a = 0; { int rem = p, q = 0; while (rem >= 7 - q){ rem -= 7 - q; q++; } a = q; }
    C2 M00 = mkc(1,0), M01 = mkc(0,0), M10 = mkc(0,0), M11 = mkc(1,0);
    for (int k = 0; k < 6; k++){
        float th = 0.5f * qw[p*6 + k];
        float s, c; sincosf(th, &s, &c);
        C2 R00, R01, R10, R11;
        int type = k % 3;
        if (type == 0){      // Rx
            R00 = mkc(c,0); R01 = mkc(0,-s); R10 = mkc(0,-s); R11 = mkc(c,0);
        } else if (type == 1){ // Ry
            R00 = mkc(c,0); R01 = mkc(-s,0); R10 = mkc(s,0); R11 = mkc(c,0);
        } else {             // Rz
            R00 = mkc(c,-s); R01 = mkc(0,0); R10 = mkc(0,0); R11 = mkc(c,s);
        }
        C2 N00 = cadd(cmul(R00,M00), cmul(R01,M10));
        C2 N01 = cadd(cmul(R00,M01), cmul(R01,M11));
        C2 N10 = cadd(cmul(R10,M00), cmul(R11,M10));
        C2 N11 = cadd(cmul(R10,M01), cmul(R11,M11));
        M00=N00; M01=N01; M10=N10; M11=N11;
    }
    float B00  = (M00.x*M00.x + M00.y*M00.y) - (M10.x*M10.x + M10.y*M10.y);
    float B11  = (M01.x*M01.x + M01.y*M01.y) - (M11.x*M11.x + M11.y*M11.y);
    float B01r = (M00.x*M01.x + M00.y*M01.y) - (M10.x*M11.x + M10.y*M11.y);
    cmat[p] = make_float4(0.5f + 0.5f*B11, 0.5f*(B00 - B11), B01r, (float)a);
}

// ---------- edge dtype probe ----------
__global__ void k_probe(const void* __restrict__ ei, int* __restrict__ flag){
    if (threadIdx.x == 0 && blockIdx.x == 0){
        const long long* e64 = (const long long*)ei;
        int ok = 1;
        for (int i = 0; i < 64; i++){
            long long v = e64[i];
            if (v < 0 || v >= N_NODES) ok = 0;
        }
        flag[0] = ok;
    }
}

__device__ inline int get_edge(const void* ei, int is64, long long idx){
    if (is64) return (int)((const long long*)ei)[idx];
    return ((const int*)ei)[idx];
}

// ---------- degree histogram over dst ----------
__global__ __launch_bounds__(256) void k_hist(const void* __restrict__ ei,
        const int* __restrict__ flag, int* __restrict__ deg){
    int e = blockIdx.x*256 + threadIdx.x;
    if (e >= N_EDGES) return;
    int is64 = flag[0];
    int dst = get_edge(ei, is64, (long long)N_EDGES + e);
    atomicAdd(&deg[dst], 1);
}

// ---------- dinv + per-bucket counts (block = one bucket of 128 nodes) ----------
__global__ __launch_bounds__(128) void k_bucket(const int* __restrict__ deg,
        float* __restrict__ dinv, int* __restrict__ bucketCnt){
    int b = blockIdx.x, t = threadIdx.x;
    int n = b*128 + t;
    int d = 0;
    if (n < N_NODES){ d = deg[n]; dinv[n] = rsqrtf((float)(d + 1)); }
    int s = d;
    #pragma unroll
    for (int m = 1; m < 64; m <<= 1) s += __shfl_xor(s, m);
    __shared__ int sh[2];
    if ((t & 63) == 0) sh[t >> 6] = s;
    __syncthreads();
    if (t == 0) bucketCnt[b] = sh[0] + sh[1];
}

// ---------- exclusive scan of bucket counts (one block) ----------
__global__ __launch_bounds__(256) void k_scanb(const int* __restrict__ bucketCnt,
        int* __restrict__ bucketStart){
    __shared__ int sh[NB_BUCKETS];
    int t = threadIdx.x;
    for (int i = t; i < NB_BUCKETS; i += 256) sh[i] = bucketCnt[i];
    __syncthreads();
    for (int ofs = 1; ofs < NB_BUCKETS; ofs <<= 1){
        int i0 = t, i1 = t + 256;
        bool a0 = i0 < NB_BUCKETS, a1 = i1 < NB_BUCKETS;
        int v0 = 0, v1 = 0;
        if (a0) v0 = sh[i0] + (i0 >= ofs ? sh[i0 - ofs] : 0);
        if (a1) v1 = sh[i1] + (i1 >= ofs ? sh[i1 - ofs] : 0);
        __syncthreads();
        if (a0) sh[i0] = v0;
        if (a1) sh[i1] = v1;
        __syncthreads();
    }
    for (int i = t; i < NB_BUCKETS; i += 256) bucketStart[i + 1] = sh[i];
    if (t == 0) bucketStart[0] = 0;
}

// ---------- LDS-staged bucket partition: pairs[] grouped by bucket ----------
// packed entry = (dst<<16) | src  (both < 65536)
__global__ __launch_bounds__(256) void k_part(const void* __restrict__ ei,
        const int* __restrict__ flag, int* __restrict__ bcnt,
        const int* __restrict__ bucketStart, unsigned* __restrict__ pairs){
    __shared__ int hist[NB_BUCKETS];     // counts -> inclusive scan
    __shared__ int cntb[NB_BUCKETS];     // saved counts
    __shared__ int cursor[NB_BUCKETS];   // scatter cursors
    __shared__ int copyBase[NB_BUCKETS]; // global dest minus local start
    __shared__ unsigned sorted[PART_CHUNK];
    int tid = threadIdx.x;
    long long base = (long long)blockIdx.x * PART_CHUNK;
    int cnt = (int)((N_EDGES - base < PART_CHUNK) ? (N_EDGES - base) : PART_CHUNK);
    for (int i = tid; i < NB_BUCKETS; i += 256) hist[i] = 0;
    __syncthreads();
    int is64 = flag[0];
    for (int i = tid; i < cnt; i += 256){
        int dst = get_edge(ei, is64, (long long)N_EDGES + base + i);
        atomicAdd(&hist[dst >> 7], 1);
    }
    __syncthreads();
    for (int i = tid; i < NB_BUCKETS; i += 256) cntb[i] = hist[i];
    __syncthreads();
    // inclusive Hillis-Steele scan of hist[0..NB_BUCKETS)
    for (int ofs = 1; ofs < NB_BUCKETS; ofs <<= 1){
        int i0 = tid, i1 = tid + 256;
        bool a0 = i0 < NB_BUCKETS, a1 = i1 < NB_BUCKETS;
        int v0 = 0, v1 = 0;
        if (a0) v0 = hist[i0] + (i0 >= ofs ? hist[i0 - ofs] : 0);
        if (a1) v1 = hist[i1] + (i1 >= ofs ? hist[i1 - ofs] : 0);
        __syncthreads();
        if (a0) hist[i0] = v0;
        if (a1) hist[i1] = v1;
        __syncthreads();
    }
    // reserve global space, set cursors to local starts
    for (int i = tid; i < NB_BUCKETS; i += 256){
        int ls = hist[i] - cntb[i];                 // local exclusive start
        int gbase = bucketStart[i] + atomicAdd(&bcnt[i], cntb[i]);
        copyBase[i] = gbase - ls;
        cursor[i] = ls;
    }
    __syncthreads();
    // scatter into LDS sorted-by-bucket
    for (int i = tid; i < cnt; i += 256){
        int src = get_edge(ei, is64, base + i);
        int dst = get_edge(ei, is64, (long long)N_EDGES + base + i);
        int pos = atomicAdd(&cursor[dst >> 7], 1);
        sorted[pos] = ((unsigned)dst << 16) | (unsigned)src;
    }
    __syncthreads();
    // dense copy-out (consecutive i -> consecutive addresses within each bucket run)
    for (int i = tid; i < cnt; i += 256){
        unsigned v = sorted[i];
        int b = (int)(v >> 23);                     // dst>>7
        pairs[copyBase[b] + i] = v;
    }
}

// ---------- per-bucket LDS counting sort + GCN gather + relu ----------
__global__ __launch_bounds__(256) void k_gs(const unsigned* __restrict__ pairs,
        const int* __restrict__ bucketStart, const float* __restrict__ z,
        const float* __restrict__ dinv, float* __restrict__ out){
    __shared__ unsigned short sorted[GS_CAP];
    __shared__ int hist[128];
    __shared__ int cursor[128];
    int b = blockIdx.x, t = threadIdx.x;
    int s0 = bucketStart[b];
    int cnt = bucketStart[b + 1] - s0;
    if (cnt > GS_CAP) cnt = GS_CAP;
    if (t < 128){ hist[t] = 0; }
    __syncthreads();
    for (int i = t; i < cnt; i += 256){
        unsigned v = pairs[s0 + i];
        atomicAdd(&hist[(v >> 16) & 127], 1);
    }
    __syncthreads();
    int mycnt = (t < 128) ? hist[t] : 0;
    // inclusive scan of hist[0..128)
    for (int ofs = 1; ofs < 128; ofs <<= 1){
        int nv = 0;
        if (t < 128) nv = hist[t] + (t >= ofs ? hist[t - ofs] : 0);
        __syncthreads();
        if (t < 128) hist[t] = nv;
        __syncthreads();
    }
    if (t < 128) cursor[t] = hist[t] - mycnt;   // exclusive start
    __syncthreads();
    for (int i = t; i < cnt; i += 256){
        unsigned v = pairs[s0 + i];
        int d = (v >> 16) & 127;
        int pos = atomicAdd(&cursor[d], 1);
        sorted[pos] = (unsigned short)(v & 0xffffu);
    }
    __syncthreads();
    // gather: 2 threads per local dst
    int d = t >> 1, half = t & 1;
    int n = b*128 + d;
    float acc[28];
    #pragma unroll
    for (int k = 0; k < 28; k++) acc[k] = 0.f;
    int hEnd = hist[d];
    int hBeg = (d == 0) ? 0 : hist[d - 1];
    if (n < N_NODES){
        for (int i = hBeg + half; i < hEnd; i += 2){
            int src = sorted[i];
            const float4* r = (const float4*)(z + (size_t)src*28);
            #pragma unroll
            for (int q = 0; q < 7; q++){
                float4 f = r[q];
                acc[4*q+0] += f.x; acc[4*q+1] += f.y;
                acc[4*q+2] += f.z; acc[4*q+3] += f.w;
            }
        }
    }
    #pragma unroll
    for (int k = 0; k < 28; k++) acc[k] += __shfl_xor(acc[k], 1);
    if (half == 0 && n < N_NODES){
        const float4* self = (const float4*)(z + (size_t)n*28);
        float dv = dinv[n];
        float4* o = (float4*)(out + (size_t)n*28);
        #pragma unroll
        for (int q = 0; q < 7; q++){
            float4 sv = self[q];
            o[q] = make_float4(fmaxf((acc[4*q+0]+sv.x)*dv, 0.f),
                               fmaxf((acc[4*q+1]+sv.y)*dv, 0.f),
                               fmaxf((acc[4*q+2]+sv.z)*dv, 0.f),
                               fmaxf((acc[4*q+3]+sv.w)*dv, 0.f));
        }
    }
}

// ---------- quantum features: one wave per node ----------
__global__ __launch_bounds__(256) void k_feat(const float* __restrict__ x,
        const float* __restrict__ dinv, const float4* __restrict__ cmat,
        float* __restrict__ z){
    int wave = threadIdx.x >> 6;
    int lane = threadIdx.x & 63;
    int n = blockIdx.x*4 + wave;
    const float4 v = ((const float4*)(x + (size_t)n*256))[lane];
    float persq = v.x*v.x + v.y*v.y + v.z*v.z + v.w*v.w;

    float red[15];
    red[0] = persq;
    red[1] = v.x*v.x + v.y*v.y;        // S0 qubit6
    red[2] = v.x*v.z + v.y*v.w;        // X qubit6
    #pragma unroll
    for (int j = 0; j < 6; j++){
        float4 pv;
        pv.x = __shfl_xor(v.x, 1 << j);
        pv.y = __shfl_xor(v.y, 1 << j);
        pv.z = __shfl_xor(v.z, 1 << j);
        pv.w = __shfl_xor(v.w, 1 << j);
        red[3 + j] = v.x*pv.x + v.y*pv.y + v.z*pv.z + v.w*pv.w;
        red[9 + j] = ((lane >> j) & 1) ? 0.0f : persq;
    }
    #pragma unroll
    for (int m = 1; m < 64; m <<= 1){
        #pragma unroll
        for (int k = 0; k < 15; k++) red[k] += __shfl_xor(red[k], m);
    }
    float s0_by_lane =
        lane == 0 ? red[14] : lane == 1 ? red[13] : lane == 2 ? red[12] :
        lane == 3 ? red[11] : lane == 4 ? red[10] : lane == 5 ? red[9]  : red[1];
    float x_by_lane =
        lane == 0 ? 0.5f*red[8] : lane == 1 ? 0.5f*red[7] : lane == 2 ? 0.5f*red[6] :
        lane == 3 ? 0.5f*red[5] : lane == 4 ? 0.5f*red[4] : lane == 5 ? 0.5f*red[3] : red[2];

    float4 cm = cmat[lane < 28 ? lane : 0];
    int ap = (int)cm.w;
    float S0a = __shfl(s0_by_lane, ap);
    float Xa  = __shfl(x_by_lane,  ap);
    float invT = 1.0f / red[0];
    float feat = cm.x + (cm.y*S0a + cm.z*Xa) * invT;
    if (lane < 28) z[(size_t)n*28 + lane] = dinv[n] * feat;
}

// ---------- Gram ----------
__global__ __launch_bounds__(256) void k_gram(const float* __restrict__ out, float* __restrict__ G){
    __shared__ float buf[64*28];
    int tid = threadIdx.x;
    int e[4]; int ii[4], jj[4]; bool val[4];
    #pragma unroll
    for (int k = 0; k < 4; k++){
        e[k] = tid + 256*k;
        val[k] = e[k] < 784;
        int ee = val[k] ? e[k] : 0;
        ii[k] = ee / 28; jj[k] = ee - 28*ii[k];
    }
    float acc[4] = {0.f, 0.f, 0.f, 0.f};
    int nchunks = (N_NODES + 63) / 64;
    for (int ch = blockIdx.x; ch < nchunks; ch += gridDim.x){
        int base = ch * 64;
        int total = (N_NODES - base < 64 ? N_NODES - base : 64) * 28;
        __syncthreads();
        for (int t = tid; t < 64*28; t += 256)
            buf[t] = (t < total) ? out[(size_t)base*28 + t] : 0.f;
        __syncthreads();
        for (int n = 0; n < 64; n++){
            const float* r = buf + n*28;
            #pragma unroll
            for (int k = 0; k < 4; k++) acc[k] += r[ii[k]] * r[jj[k]];
        }
    }
    #pragma unroll
    for (int k = 0; k < 4; k++) if (val[k]) atomicAdd(&G[e[k]], acc[k]);
}

// ---------- MLP ----------
__global__ __launch_bounds__(256) void k_mlp1(const float* __restrict__ G,
        const float* __restrict__ W1, const float* __restrict__ b1, float* __restrict__ h){
    int j = blockIdx.x;
    const float* w = W1 + (size_t)j*784;
    float s = 0.f;
    for (int i = threadIdx.x; i < 784; i += 256) s += G[i] * w[i];
    __shared__ float sh[256];
    sh[threadIdx.x] = s; __syncthreads();
    for (int ofs = 128; ofs > 0; ofs >>= 1){
        if (threadIdx.x < ofs) sh[threadIdx.x] += sh[threadIdx.x + ofs];
        __syncthreads();
    }
    if (threadIdx.x == 0) h[j] = fmaxf(sh[0] + b1[j], 0.f);
}

__global__ void k_mlp2(const float* __restrict__ h, const float* __restrict__ W2,
        const float* __restrict__ b2, float* __restrict__ outp){
    __shared__ float sh[128];
    int t = threadIdx.x;
    sh[t] = h[t] * W2[t];
    __syncthreads();
    for (int ofs = 64; ofs > 0; ofs >>= 1){
        if (t < ofs) sh[t] += sh[t + ofs];
        __syncthreads();
    }
    if (t == 0) outp[0] = 1.f / (1.f + expf(-(sh[0] + b2[0])));
}

extern "C" void kernel_launch(void* const* d_in, const int* in_sizes, int n_in,
                              void* d_out, int out_size, void* d_ws, size_t ws_size,
                              hipStream_t stream){
    const float* x  = (const float*)d_in[0];
    const void*  ei = d_in[1];
    const float* qw = (const float*)d_in[2];
    const float* W1 = (const float*)d_in[3];
    const float* b1 = (const float*)d_in[4];
    const float* W2 = (const float*)d_in[5];
    const float* b2 = (const float*)d_in[6];
    float* outp = (float*)d_out;

    char* base = (char*)d_ws;
    float*    z     = (float*)base;    base += (size_t)N_NODES*28*4;
    float*    ob    = (float*)base;    base += (size_t)N_NODES*28*4;
    unsigned* pairs = (unsigned*)base; base += (size_t)N_EDGES*4;
    int*      deg   = (int*)base;      base += (size_t)N_NODES*4;
    float*    dinv  = (float*)base;    base += (size_t)N_NODES*4;
    int*      bucketCnt   = (int*)base; base += 2048;
    int*      bucketStart = (int*)base; base += 2048;
    int*      bcnt  = (int*)base;      base += 2048;
    float4*   cmat  = (float4*)base;   base += 448;
    float*    G     = (float*)base;    base += 784*4;
    float*    h     = (float*)base;    base += 512;
    int*      flag  = (int*)base;      base += 16;

    hipMemsetAsync(deg, 0, (size_t)N_NODES*4, stream);
    hipMemsetAsync(bcnt, 0, 2048, stream);
    hipMemsetAsync(G,   0, 784*4, stream);

    int nbE = (N_EDGES + 255) / 256;                 // 6250
    int nbP = (N_EDGES + PART_CHUNK - 1) / PART_CHUNK; // 196

    k_probe<<<1, 64, 0, stream>>>(ei, flag);
    k_pairs<<<1, 32, 0, stream>>>(qw, cmat);
    k_hist<<<nbE, 256, 0, stream>>>(ei, flag, deg);
    k_bucket<<<NB_BUCKETS, 128, 0, stream>>>(deg, dinv, bucketCnt);
    k_scanb<<<1, 256, 0, stream>>>(bucketCnt, bucketStart);
    k_part<<<nbP, 256, 0, stream>>>(ei, flag, bcnt, bucketStart, pairs);
    k_feat<<<N_NODES/4, 256, 0, stream>>>(x, dinv, cmat, z);
    k_gs<<<NB_BUCKETS, 256, 0, stream>>>(pairs, bucketStart, z, dinv, ob);
    k_gram<<<196, 256, 0, stream>>>(ob, G);
    k_mlp1<<<128, 256, 0, stream>>>(G, W1, b1, h);
    k_mlp2<<<1, 128, 0, stream>>>(h, W2, b2, outp);
}

// Round 3
// 283.188 us; speedup vs baseline: 1.4042x; 1.2137x over previous
//
#include <hip/hip_runtime.h>
#include <math.h>

#define N_NODES 50000
#define N_EDGES 1600000
#define NB_BUCKETS 391      // ceil(50000/128), bucket = dst>>7
#define PART_CHUNK 8192
#define NCHUNK 196          // ceil(N_EDGES / PART_CHUNK)
#define GS_CAP 6144

// ---------- complex 2x2 helpers ----------
struct C2 { float x, y; };
__device__ inline C2 mkc(float x, float y){ C2 r; r.x=x; r.y=y; return r; }
__device__ inline C2 cmul(C2 a, C2 b){ return mkc(a.x*b.x - a.y*b.y, a.x*b.y + a.y*b.x); }
__device__ inline C2 cadd(C2 a, C2 b){ return mkc(a.x+b.x, a.y+b.y); }

// ---------- per-pair observable B = A^dag Z A folded into feature coeffs ----------
__global__ void k_pairs(const float* __restrict__ qw, float4* __restrict__ cmat){
    int p = blockIdx.x*blockDim.x + threadIdx.x;
    if (p >= 28) return;
    int a = 0; { int rem = p, q = 0; while (rem >= 7 - q){ rem -= 7 - q; q++; } a = q; }
    C2 M00 = mkc(1,0), M01 = mkc(0,0), M10 = mkc(0,0), M11 = mkc(1,0);
    for (int k = 0; k < 6; k++){
        float th = 0.5f * qw[p*6 + k];
        float s, c; sincosf(th, &s, &c);
        C2 R00, R01, R10, R11;
        int type = k % 3;
        if (type == 0){      // Rx
            R00 = mkc(c,0); R01 = mkc(0,-s); R10 = mkc(0,-s); R11 = mkc(c,0);
        } else if (type == 1){ // Ry
            R00 = mkc(c,0); R01 = mkc(-s,0); R10 = mkc(s,0); R11 = mkc(c,0);
        } else {             // Rz
            R00 = mkc(c,-s); R01 = mkc(0,0); R10 = mkc(0,0); R11 = mkc(c,s);
        }
        C2 N00 = cadd(cmul(R00,M00), cmul(R01,M10));
        C2 N01 = cadd(cmul(R00,M01), cmul(R01,M11));
        C2 N10 = cadd(cmul(R10,M00), cmul(R11,M10));
        C2 N11 = cadd(cmul(R10,M01), cmul(R11,M11));
        M00=N00; M01=N01; M10=N10; M11=N11;
    }
    float B00  = (M00.x*M00.x + M00.y*M00.y) - (M10.x*M10.x + M10.y*M10.y);
    float B11  = (M01.x*M01.x + M01.y*M01.y) - (M11.x*M11.x + M11.y*M11.y);
    float B01r = (M00.x*M01.x + M00.y*M01.y) - (M10.x*M11.x + M10.y*M11.y);
    cmat[p] = make_float4(0.5f + 0.5f*B11, 0.5f*(B00 - B11), B01r, (float)a);
}

// ---------- edge dtype probe ----------
__global__ void k_probe(const void* __restrict__ ei, int* __restrict__ flag){
    if (threadIdx.x == 0 && blockIdx.x == 0){
        const long long* e64 = (const long long*)ei;
        int ok = 1;
        for (int i = 0; i < 64; i++){
            long long v = e64[i];
            if (v < 0 || v >= N_NODES) ok = 0;
        }
        flag[0] = ok;
    }
}

__device__ inline int get_edge(const void* ei, int is64, long long idx){
    if (is64) return (int)((const long long*)ei)[idx];
    return ((const int*)ei)[idx];
}

// ---------- pass 1: per-chunk bucket histogram (dst only, no global atomics) ----------
__global__ __launch_bounds__(256) void k_part1(const void* __restrict__ ei,
        const int* __restrict__ flag, int* __restrict__ chunkCnt){
    __shared__ int hist[NB_BUCKETS];
    int tid = threadIdx.x, c = blockIdx.x;
    long long base = (long long)c * PART_CHUNK;
    int cnt = (int)((N_EDGES - base < PART_CHUNK) ? (N_EDGES - base) : PART_CHUNK);
    for (int i = tid; i < NB_BUCKETS; i += 256) hist[i] = 0;
    __syncthreads();
    int is64 = flag[0];
    for (int i = tid; i < cnt; i += 256){
        int dst = get_edge(ei, is64, (long long)N_EDGES + base + i);
        atomicAdd(&hist[dst >> 7], 1);
    }
    __syncthreads();
    for (int i = tid; i < NB_BUCKETS; i += 256)
        chunkCnt[i*NCHUNK + c] = hist[i];
}

// ---------- per-bucket exclusive scan over chunks (in place) + bucket totals ----------
__global__ __launch_bounds__(256) void k_chunkscan(int* __restrict__ chunkCnt,
        int* __restrict__ bucketCnt){
    __shared__ int sh[256];
    int b = blockIdx.x, t = threadIdx.x;
    int v = (t < NCHUNK) ? chunkCnt[b*NCHUNK + t] : 0;
    sh[t] = v; __syncthreads();
    for (int ofs = 1; ofs < 256; ofs <<= 1){
        int u = (t >= ofs) ? sh[t - ofs] : 0; __syncthreads();
        sh[t] += u; __syncthreads();
    }
    if (t < NCHUNK) chunkCnt[b*NCHUNK + t] = sh[t] - v;  // exclusive
    if (t == 255) bucketCnt[b] = sh[255];
}

// ---------- exclusive scan of bucket counts (one block) ----------
__global__ __launch_bounds__(256) void k_scanb(const int* __restrict__ bucketCnt,
        int* __restrict__ bucketStart){
    __shared__ int sh[NB_BUCKETS];
    int t = threadIdx.x;
    for (int i = t; i < NB_BUCKETS; i += 256) sh[i] = bucketCnt[i];
    __syncthreads();
    for (int ofs = 1; ofs < NB_BUCKETS; ofs <<= 1){
        int i0 = t, i1 = t + 256;
        bool a0 = i0 < NB_BUCKETS, a1 = i1 < NB_BUCKETS;
        int v0 = 0, v1 = 0;
        if (a0) v0 = sh[i0] + (i0 >= ofs ? sh[i0 - ofs] : 0);
        if (a1) v1 = sh[i1] + (i1 >= ofs ? sh[i1 - ofs] : 0);
        __syncthreads();
        if (a0) sh[i0] = v0;
        if (a1) sh[i1] = v1;
        __syncthreads();
    }
    for (int i = t; i < NB_BUCKETS; i += 256) bucketStart[i + 1] = sh[i];
    if (t == 0) bucketStart[0] = 0;
}

// ---------- pass 2: LDS bucket-sort chunk, deterministic dense copy-out ----------
// packed entry = (dst<<16) | src
__global__ __launch_bounds__(256) void k_part2(const void* __restrict__ ei,
        const int* __restrict__ flag, const int* __restrict__ chunkCnt,
        const int* __restrict__ bucketStart, unsigned* __restrict__ pairs){
    __shared__ int hist[NB_BUCKETS];
    __shared__ int cntb[NB_BUCKETS];
    __shared__ int cursor[NB_BUCKETS];
    __shared__ int copyBase[NB_BUCKETS];
    __shared__ unsigned sorted[PART_CHUNK];
    int tid = threadIdx.x, c = blockIdx.x;
    long long base = (long long)c * PART_CHUNK;
    int cnt = (int)((N_EDGES - base < PART_CHUNK) ? (N_EDGES - base) : PART_CHUNK);
    for (int i = tid; i < NB_BUCKETS; i += 256) hist[i] = 0;
    __syncthreads();
    int is64 = flag[0];
    for (int i = tid; i < cnt; i += 256){
        int dst = get_edge(ei, is64, (long long)N_EDGES + base + i);
        atomicAdd(&hist[dst >> 7], 1);
    }
    __syncthreads();
    for (int i = tid; i < NB_BUCKETS; i += 256) cntb[i] = hist[i];
    __syncthreads();
    for (int ofs = 1; ofs < NB_BUCKETS; ofs <<= 1){
        int i0 = tid, i1 = tid + 256;
        bool a0 = i0 < NB_BUCKETS, a1 = i1 < NB_BUCKETS;
        int v0 = 0, v1 = 0;
        if (a0) v0 = hist[i0] + (i0 >= ofs ? hist[i0 - ofs] : 0);
        if (a1) v1 = hist[i1] + (i1 >= ofs ? hist[i1 - ofs] : 0);
        __syncthreads();
        if (a0) hist[i0] = v0;
        if (a1) hist[i1] = v1;
        __syncthreads();
    }
    for (int i = tid; i < NB_BUCKETS; i += 256){
        int ls = hist[i] - cntb[i];                    // local exclusive start
        int gbase = bucketStart[i] + chunkCnt[i*NCHUNK + c];
        copyBase[i] = gbase - ls;
        cursor[i] = ls;
    }
    __syncthreads();
    for (int i = tid; i < cnt; i += 256){
        int src = get_edge(ei, is64, base + i);
        int dst = get_edge(ei, is64, (long long)N_EDGES + base + i);
        int pos = atomicAdd(&cursor[dst >> 7], 1);
        sorted[pos] = ((unsigned)dst << 16) | (unsigned)src;
    }
    __syncthreads();
    for (int i = tid; i < cnt; i += 256){
        unsigned v = sorted[i];
        int b = (int)(v >> 23);                        // dst>>7
        pairs[copyBase[b] + i] = v;
    }
}

// ---------- per-bucket degree + dinv from partitioned pairs ----------
__global__ __launch_bounds__(256) void k_deg(const unsigned* __restrict__ pairs,
        const int* __restrict__ bucketStart, float* __restrict__ dinv){
    __shared__ int hist[128];
    int b = blockIdx.x, t = threadIdx.x;
    int s0 = bucketStart[b];
    int cnt = bucketStart[b + 1] - s0;
    if (t < 128) hist[t] = 0;
    __syncthreads();
    for (int i = t; i < cnt; i += 256){
        unsigned v = pairs[s0 + i];
        atomicAdd(&hist[(v >> 16) & 127], 1);
    }
    __syncthreads();
    if (t < 128){
        int n = b*128 + t;
        if (n < N_NODES) dinv[n] = rsqrtf((float)(hist[t] + 1));
    }
}

// ---------- per-bucket LDS counting sort + GCN gather + relu ----------
__global__ __launch_bounds__(256) void k_gs(const unsigned* __restrict__ pairs,
        const int* __restrict__ bucketStart, const float* __restrict__ z,
        const float* __restrict__ dinv, float* __restrict__ out){
    __shared__ unsigned short sorted[GS_CAP];
    __shared__ int hist[128];
    __shared__ int cursor[128];
    int b = blockIdx.x, t = threadIdx.x;
    int s0 = bucketStart[b];
    int cnt = bucketStart[b + 1] - s0;
    if (cnt > GS_CAP) cnt = GS_CAP;
    if (t < 128){ hist[t] = 0; }
    __syncthreads();
    for (int i = t; i < cnt; i += 256){
        unsigned v = pairs[s0 + i];
        atomicAdd(&hist[(v >> 16) & 127], 1);
    }
    __syncthreads();
    int mycnt = (t < 128) ? hist[t] : 0;
    for (int ofs = 1; ofs < 128; ofs <<= 1){
        int nv = 0;
        if (t < 128) nv = hist[t] + (t >= ofs ? hist[t - ofs] : 0);
        __syncthreads();
        if (t < 128) hist[t] = nv;
        __syncthreads();
    }
    if (t < 128) cursor[t] = hist[t] - mycnt;
    __syncthreads();
    for (int i = t; i < cnt; i += 256){
        unsigned v = pairs[s0 + i];
        int d = (v >> 16) & 127;
        int pos = atomicAdd(&cursor[d], 1);
        sorted[pos] = (unsigned short)(v & 0xffffu);
    }
    __syncthreads();
    int d = t >> 1, half = t & 1;
    int n = b*128 + d;
    float acc[28];
    #pragma unroll
    for (int k = 0; k < 28; k++) acc[k] = 0.f;
    int hEnd = hist[d];
    int hBeg = (d == 0) ? 0 : hist[d - 1];
    if (n < N_NODES){
        for (int i = hBeg + half; i < hEnd; i += 2){
            int src = sorted[i];
            const float4* r = (const float4*)(z + (size_t)src*28);
            #pragma unroll
            for (int q = 0; q < 7; q++){
                float4 f = r[q];
                acc[4*q+0] += f.x; acc[4*q+1] += f.y;
                acc[4*q+2] += f.z; acc[4*q+3] += f.w;
            }
        }
    }
    #pragma unroll
    for (int k = 0; k < 28; k++) acc[k] += __shfl_xor(acc[k], 1);
    if (half == 0 && n < N_NODES){
        const float4* self = (const float4*)(z + (size_t)n*28);
        float dv = dinv[n];
        float4* o = (float4*)(out + (size_t)n*28);
        #pragma unroll
        for (int q = 0; q < 7; q++){
            float4 sv = self[q];
            o[q] = make_float4(fmaxf((acc[4*q+0]+sv.x)*dv, 0.f),
                               fmaxf((acc[4*q+1]+sv.y)*dv, 0.f),
                               fmaxf((acc[4*q+2]+sv.z)*dv, 0.f),
                               fmaxf((acc[4*q+3]+sv.w)*dv, 0.f));
        }
    }
}

// ---------- quantum features: one wave per node ----------
__global__ __launch_bounds__(256) void k_feat(const float* __restrict__ x,
        const float* __restrict__ dinv, const float4* __restrict__ cmat,
        float* __restrict__ z){
    int wave = threadIdx.x >> 6;
    int lane = threadIdx.x & 63;
    int n = blockIdx.x*4 + wave;
    const float4 v = ((const float4*)(x + (size_t)n*256))[lane];
    float persq = v.x*v.x + v.y*v.y + v.z*v.z + v.w*v.w;

    float red[15];
    red[0] = persq;
    red[1] = v.x*v.x + v.y*v.y;        // S0 qubit6
    red[2] = v.x*v.z + v.y*v.w;        // X qubit6
    #pragma unroll
    for (int j = 0; j < 6; j++){
        float4 pv;
        pv.x = __shfl_xor(v.x, 1 << j);
        pv.y = __shfl_xor(v.y, 1 << j);
        pv.z = __shfl_xor(v.z, 1 << j);
        pv.w = __shfl_xor(v.w, 1 << j);
        red[3 + j] = v.x*pv.x + v.y*pv.y + v.z*pv.z + v.w*pv.w;
        red[9 + j] = ((lane >> j) & 1) ? 0.0f : persq;
    }
    #pragma unroll
    for (int m = 1; m < 64; m <<= 1){
        #pragma unroll
        for (int k = 0; k < 15; k++) red[k] += __shfl_xor(red[k], m);
    }
    float s0_by_lane =
        lane == 0 ? red[14] : lane == 1 ? red[13] : lane == 2 ? red[12] :
        lane == 3 ? red[11] : lane == 4 ? red[10] : lane == 5 ? red[9]  : red[1];
    float x_by_lane =
        lane == 0 ? 0.5f*red[8] : lane == 1 ? 0.5f*red[7] : lane == 2 ? 0.5f*red[6] :
        lane == 3 ? 0.5f*red[5] : lane == 4 ? 0.5f*red[4] : lane == 5 ? 0.5f*red[3] : red[2];

    float4 cm = cmat[lane < 28 ? lane : 0];
    int ap = (int)cm.w;
    float S0a = __shfl(s0_by_lane, ap);
    float Xa  = __shfl(x_by_lane,  ap);
    float invT = 1.0f / red[0];
    float feat = cm.x + (cm.y*S0a + cm.z*Xa) * invT;
    if (lane < 28) z[(size_t)n*28 + lane] = dinv[n] * feat;
}

// ---------- Gram ----------
__global__ __launch_bounds__(256) void k_gram(const float* __restrict__ out, float* __restrict__ G){
    __shared__ float buf[64*28];
    int tid = threadIdx.x;
    int e[4]; int ii[4], jj[4]; bool val[4];
    #pragma unroll
    for (int k = 0; k < 4; k++){
        e[k] = tid + 256*k;
        val[k] = e[k] < 784;
        int ee = val[k] ? e[k] : 0;
        ii[k] = ee / 28; jj[k] = ee - 28*ii[k];
    }
    float acc[4] = {0.f, 0.f, 0.f, 0.f};
    int nchunks = (N_NODES + 63) / 64;
    for (int ch = blockIdx.x; ch < nchunks; ch += gridDim.x){
        int base = ch * 64;
        int total = (N_NODES - base < 64 ? N_NODES - base : 64) * 28;
        __syncthreads();
        for (int t = tid; t < 64*28; t += 256)
            buf[t] = (t < total) ? out[(size_t)base*28 + t] : 0.f;
        __syncthreads();
        for (int n = 0; n < 64; n++){
            const float* r = buf + n*28;
            #pragma unroll
            for (int k = 0; k < 4; k++) acc[k] += r[ii[k]] * r[jj[k]];
        }
    }
    #pragma unroll
    for (int k = 0; k < 4; k++) if (val[k]) atomicAdd(&G[e[k]], acc[k]);
}

// ---------- MLP ----------
__global__ __launch_bounds__(256) void k_mlp1(const float* __restrict__ G,
        const float* __restrict__ W1, const float* __restrict__ b1, float* __restrict__ h){
    int j = blockIdx.x;
    const float* w = W1 + (size_t)j*784;
    float s = 0.f;
    for (int i = threadIdx.x; i < 784; i += 256) s += G[i] * w[i];
    __shared__ float sh[256];
    sh[threadIdx.x] = s; __syncthreads();
    for (int ofs = 128; ofs > 0; ofs >>= 1){
        if (threadIdx.x < ofs) sh[threadIdx.x] += sh[threadIdx.x + ofs];
        __syncthreads();
    }
    if (threadIdx.x == 0) h[j] = fmaxf(sh[0] + b1[j], 0.f);
}

__global__ void k_mlp2(const float* __restrict__ h, const float* __restrict__ W2,
        const float* __restrict__ b2, float* __restrict__ outp){
    __shared__ float sh[128];
    int t = threadIdx.x;
    sh[t] = h[t] * W2[t];
    __syncthreads();
    for (int ofs = 64; ofs > 0; ofs >>= 1){
        if (t < ofs) sh[t] += sh[t + ofs];
        __syncthreads();
    }
    if (t == 0) outp[0] = 1.f / (1.f + expf(-(sh[0] + b2[0])));
}

extern "C" void kernel_launch(void* const* d_in, const int* in_sizes, int n_in,
                              void* d_out, int out_size, void* d_ws, size_t ws_size,
                              hipStream_t stream){
    const float* x  = (const float*)d_in[0];
    const void*  ei = d_in[1];
    const float* qw = (const float*)d_in[2];
    const float* W1 = (const float*)d_in[3];
    const float* b1 = (const float*)d_in[4];
    const float* W2 = (const float*)d_in[5];
    const float* b2 = (const float*)d_in[6];
    float* outp = (float*)d_out;

    char* base = (char*)d_ws;
    float*    z     = (float*)base;    base += (size_t)N_NODES*28*4;
    float*    ob    = (float*)base;    base += (size_t)N_NODES*28*4;
    unsigned* pairs = (unsigned*)base; base += (size_t)N_EDGES*4;
    float*    dinv  = (float*)base;    base += (size_t)N_NODES*4;
    int*      chunkCnt    = (int*)base; base += (size_t)NB_BUCKETS*NCHUNK*4;
    int*      bucketCnt   = (int*)base; base += 2048;
    int*      bucketStart = (int*)base; base += 2048;
    float4*   cmat  = (float4*)base;   base += 448;
    float*    G     = (float*)base;    base += 784*4;
    float*    h     = (float*)base;    base += 512;
    int*      flag  = (int*)base;      base += 16;

    hipMemsetAsync(G, 0, 784*4, stream);

    k_probe<<<1, 64, 0, stream>>>(ei, flag);
    k_pairs<<<1, 32, 0, stream>>>(qw, cmat);
    k_part1<<<NCHUNK, 256, 0, stream>>>(ei, flag, chunkCnt);
    k_chunkscan<<<NB_BUCKETS, 256, 0, stream>>>(chunkCnt, bucketCnt);
    k_scanb<<<1, 256, 0, stream>>>(bucketCnt, bucketStart);
    k_part2<<<NCHUNK, 256, 0, stream>>>(ei, flag, chunkCnt, bucketStart, pairs);
    k_deg<<<NB_BUCKETS, 256, 0, stream>>>(pairs, bucketStart, dinv);
    k_feat<<<N_NODES/4, 256, 0, stream>>>(x, dinv, cmat, z);
    k_gs<<<NB_BUCKETS, 256, 0, stream>>>(pairs, bucketStart, z, dinv, ob);
    k_gram<<<196, 256, 0, stream>>>(ob, G);
    k_mlp1<<<128, 256, 0, stream>>>(G, W1, b1, h);
    k_mlp2<<<1, 128, 0, stream>>>(h, W2, b2, outp);
}

// Round 4
// 243.809 us; speedup vs baseline: 1.6310x; 1.1615x over previous
//
#include <hip/hip_runtime.h>
#include <math.h>

#define N_NODES 50000
#define N_EDGES 1600000
#define NB_BUCKETS 391      // ceil(50000/128), bucket = dst>>7
#define PART_CHUNK 8192
#define NCHUNK 196          // ceil(N_EDGES / PART_CHUNK)
#define GS_CAP 6144

// ---------- DPP helpers (VALU-pipe cross-lane, no LDS) ----------
template<int CTRL>
__device__ inline float dpp_mov(float x){
    return __int_as_float(__builtin_amdgcn_update_dpp(0, __float_as_int(x), CTRL, 0xf, 0xf, false));
}
// full wave64 sum; total lands in lane 63
__device__ inline float wave_sum_dpp(float x){
    x += dpp_mov<0x111>(x);   // row_shr:1
    x += dpp_mov<0x112>(x);   // row_shr:2
    x += dpp_mov<0x114>(x);   // row_shr:4
    x += dpp_mov<0x118>(x);   // row_shr:8
    x += dpp_mov<0x142>(x);   // row_bcast:15
    x += dpp_mov<0x143>(x);   // row_bcast:31
    return x;
}
__device__ inline float lane63(float x){
    return __int_as_float(__builtin_amdgcn_readlane(__float_as_int(x), 63));
}
#define DPP_XOR1 0xB1   // quad_perm [1,0,3,2]
#define DPP_XOR2 0x4E   // quad_perm [2,3,0,1]

// ---------- complex 2x2 helpers ----------
struct C2 { float x, y; };
__device__ inline C2 mkc(float x, float y){ C2 r; r.x=x; r.y=y; return r; }
__device__ inline C2 cmul(C2 a, C2 b){ return mkc(a.x*b.x - a.y*b.y, a.x*b.y + a.y*b.x); }
__device__ inline C2 cadd(C2 a, C2 b){ return mkc(a.x+b.x, a.y+b.y); }

// ---------- per-pair observable B = A^dag Z A folded into feature coeffs ----------
__global__ void k_pairs(const float* __restrict__ qw, float4* __restrict__ cmat){
    int p = blockIdx.x*blockDim.x + threadIdx.x;
    if (p >= 28) return;
    int a = 0; { int rem = p, q = 0; while (rem >= 7 - q){ rem -= 7 - q; q++; } a = q; }
    C2 M00 = mkc(1,0), M01 = mkc(0,0), M10 = mkc(0,0), M11 = mkc(1,0);
    for (int k = 0; k < 6; k++){
        float th = 0.5f * qw[p*6 + k];
        float s, c; sincosf(th, &s, &c);
        C2 R00, R01, R10, R11;
        int type = k % 3;
        if (type == 0){      // Rx
            R00 = mkc(c,0); R01 = mkc(0,-s); R10 = mkc(0,-s); R11 = mkc(c,0);
        } else if (type == 1){ // Ry
            R00 = mkc(c,0); R01 = mkc(-s,0); R10 = mkc(s,0); R11 = mkc(c,0);
        } else {             // Rz
            R00 = mkc(c,-s); R01 = mkc(0,0); R10 = mkc(0,0); R11 = mkc(c,s);
        }
        C2 N00 = cadd(cmul(R00,M00), cmul(R01,M10));
        C2 N01 = cadd(cmul(R00,M01), cmul(R01,M11));
        C2 N10 = cadd(cmul(R10,M00), cmul(R11,M10));
        C2 N11 = cadd(cmul(R10,M01), cmul(R11,M11));
        M00=N00; M01=N01; M10=N10; M11=N11;
    }
    float B00  = (M00.x*M00.x + M00.y*M00.y) - (M10.x*M10.x + M10.y*M10.y);
    float B11  = (M01.x*M01.x + M01.y*M01.y) - (M11.x*M11.x + M11.y*M11.y);
    float B01r = (M00.x*M01.x + M00.y*M01.y) - (M10.x*M11.x + M10.y*M11.y);
    cmat[p] = make_float4(0.5f + 0.5f*B11, 0.5f*(B00 - B11), B01r, (float)a);
}

// ---------- edge dtype probe ----------
__global__ void k_probe(const void* __restrict__ ei, int* __restrict__ flag){
    if (threadIdx.x == 0 && blockIdx.x == 0){
        const long long* e64 = (const long long*)ei;
        int ok = 1;
        for (int i = 0; i < 64; i++){
            long long v = e64[i];
            if (v < 0 || v >= N_NODES) ok = 0;
        }
        flag[0] = ok;
    }
}

__device__ inline int get_edge(const void* ei, int is64, long long idx){
    if (is64) return (int)((const long long*)ei)[idx];
    return ((const int*)ei)[idx];
}

// ---------- pass 1: per-chunk bucket histogram ----------
__global__ __launch_bounds__(256) void k_part1(const void* __restrict__ ei,
        const int* __restrict__ flag, int* __restrict__ chunkCnt){
    __shared__ int hist[NB_BUCKETS];
    int tid = threadIdx.x, c = blockIdx.x;
    long long base = (long long)c * PART_CHUNK;
    int cnt = (int)((N_EDGES - base < PART_CHUNK) ? (N_EDGES - base) : PART_CHUNK);
    for (int i = tid; i < NB_BUCKETS; i += 256) hist[i] = 0;
    __syncthreads();
    int is64 = flag[0];
    for (int i = tid; i < cnt; i += 256){
        int dst = get_edge(ei, is64, (long long)N_EDGES + base + i);
        atomicAdd(&hist[dst >> 7], 1);
    }
    __syncthreads();
    for (int i = tid; i < NB_BUCKETS; i += 256)
        chunkCnt[i*NCHUNK + c] = hist[i];
}

// ---------- per-bucket exclusive scan over chunks (in place) + bucket totals ----------
__global__ __launch_bounds__(256) void k_chunkscan(int* __restrict__ chunkCnt,
        int* __restrict__ bucketCnt){
    __shared__ int sh[256];
    int b = blockIdx.x, t = threadIdx.x;
    int v = (t < NCHUNK) ? chunkCnt[b*NCHUNK + t] : 0;
    sh[t] = v; __syncthreads();
    for (int ofs = 1; ofs < 256; ofs <<= 1){
        int u = (t >= ofs) ? sh[t - ofs] : 0; __syncthreads();
        sh[t] += u; __syncthreads();
    }
    if (t < NCHUNK) chunkCnt[b*NCHUNK + t] = sh[t] - v;  // exclusive
    if (t == 255) bucketCnt[b] = sh[255];
}

// ---------- exclusive scan of bucket counts (one block) ----------
__global__ __launch_bounds__(256) void k_scanb(const int* __restrict__ bucketCnt,
        int* __restrict__ bucketStart){
    __shared__ int sh[NB_BUCKETS];
    int t = threadIdx.x;
    for (int i = t; i < NB_BUCKETS; i += 256) sh[i] = bucketCnt[i];
    __syncthreads();
    for (int ofs = 1; ofs < NB_BUCKETS; ofs <<= 1){
        int i0 = t, i1 = t + 256;
        bool a0 = i0 < NB_BUCKETS, a1 = i1 < NB_BUCKETS;
        int v0 = 0, v1 = 0;
        if (a0) v0 = sh[i0] + (i0 >= ofs ? sh[i0 - ofs] : 0);
        if (a1) v1 = sh[i1] + (i1 >= ofs ? sh[i1 - ofs] : 0);
        __syncthreads();
        if (a0) sh[i0] = v0;
        if (a1) sh[i1] = v1;
        __syncthreads();
    }
    for (int i = t; i < NB_BUCKETS; i += 256) bucketStart[i + 1] = sh[i];
    if (t == 0) bucketStart[0] = 0;
}

// ---------- pass 2: LDS bucket-sort chunk, deterministic dense copy-out ----------
__global__ __launch_bounds__(256) void k_part2(const void* __restrict__ ei,
        const int* __restrict__ flag, const int* __restrict__ chunkCnt,
        const int* __restrict__ bucketStart, unsigned* __restrict__ pairs){
    __shared__ int hist[NB_BUCKETS];
    __shared__ int cntb[NB_BUCKETS];
    __shared__ int cursor[NB_BUCKETS];
    __shared__ int copyBase[NB_BUCKETS];
    __shared__ unsigned sorted[PART_CHUNK];
    int tid = threadIdx.x, c = blockIdx.x;
    long long base = (long long)c * PART_CHUNK;
    int cnt = (int)((N_EDGES - base < PART_CHUNK) ? (N_EDGES - base) : PART_CHUNK);
    for (int i = tid; i < NB_BUCKETS; i += 256) hist[i] = 0;
    __syncthreads();
    int is64 = flag[0];
    for (int i = tid; i < cnt; i += 256){
        int dst = get_edge(ei, is64, (long long)N_EDGES + base + i);
        atomicAdd(&hist[dst >> 7], 1);
    }
    __syncthreads();
    for (int i = tid; i < NB_BUCKETS; i += 256) cntb[i] = hist[i];
    __syncthreads();
    for (int ofs = 1; ofs < NB_BUCKETS; ofs <<= 1){
        int i0 = tid, i1 = tid + 256;
        bool a0 = i0 < NB_BUCKETS, a1 = i1 < NB_BUCKETS;
        int v0 = 0, v1 = 0;
        if (a0) v0 = hist[i0] + (i0 >= ofs ? hist[i0 - ofs] : 0);
        if (a1) v1 = hist[i1] + (i1 >= ofs ? hist[i1 - ofs] : 0);
        __syncthreads();
        if (a0) hist[i0] = v0;
        if (a1) hist[i1] = v1;
        __syncthreads();
    }
    for (int i = tid; i < NB_BUCKETS; i += 256){
        int ls = hist[i] - cntb[i];
        int gbase = bucketStart[i] + chunkCnt[i*NCHUNK + c];
        copyBase[i] = gbase - ls;
        cursor[i] = ls;
    }
    __syncthreads();
    for (int i = tid; i < cnt; i += 256){
        int src = get_edge(ei, is64, base + i);
        int dst = get_edge(ei, is64, (long long)N_EDGES + base + i);
        int pos = atomicAdd(&cursor[dst >> 7], 1);
        sorted[pos] = ((unsigned)dst << 16) | (unsigned)src;
    }
    __syncthreads();
    for (int i = tid; i < cnt; i += 256){
        unsigned v = sorted[i];
        int b = (int)(v >> 23);
        pairs[copyBase[b] + i] = v;
    }
}

// ---------- per-bucket degree + dinv ----------
__global__ __launch_bounds__(256) void k_deg(const unsigned* __restrict__ pairs,
        const int* __restrict__ bucketStart, float* __restrict__ dinv){
    __shared__ int hist[128];
    int b = blockIdx.x, t = threadIdx.x;
    int s0 = bucketStart[b];
    int cnt = bucketStart[b + 1] - s0;
    if (t < 128) hist[t] = 0;
    __syncthreads();
    for (int i = t; i < cnt; i += 256){
        unsigned v = pairs[s0 + i];
        atomicAdd(&hist[(v >> 16) & 127], 1);
    }
    __syncthreads();
    if (t < 128){
        int n = b*128 + t;
        if (n < N_NODES) dinv[n] = rsqrtf((float)(hist[t] + 1));
    }
}

// ---------- per-bucket LDS counting sort + GCN gather + relu ----------
__global__ __launch_bounds__(256) void k_gs(const unsigned* __restrict__ pairs,
        const int* __restrict__ bucketStart, const float* __restrict__ z,
        const float* __restrict__ dinv, float* __restrict__ out){
    __shared__ unsigned short sorted[GS_CAP];
    __shared__ int hist[128];
    __shared__ int cursor[128];
    int b = blockIdx.x, t = threadIdx.x;
    int s0 = bucketStart[b];
    int cnt = bucketStart[b + 1] - s0;
    if (cnt > GS_CAP) cnt = GS_CAP;
    if (t < 128){ hist[t] = 0; }
    __syncthreads();
    for (int i = t; i < cnt; i += 256){
        unsigned v = pairs[s0 + i];
        atomicAdd(&hist[(v >> 16) & 127], 1);
    }
    __syncthreads();
    int mycnt = (t < 128) ? hist[t] : 0;
    for (int ofs = 1; ofs < 128; ofs <<= 1){
        int nv = 0;
        if (t < 128) nv = hist[t] + (t >= ofs ? hist[t - ofs] : 0);
        __syncthreads();
        if (t < 128) hist[t] = nv;
        __syncthreads();
    }
    if (t < 128) cursor[t] = hist[t] - mycnt;
    __syncthreads();
    for (int i = t; i < cnt; i += 256){
        unsigned v = pairs[s0 + i];
        int d = (v >> 16) & 127;
        int pos = atomicAdd(&cursor[d], 1);
        sorted[pos] = (unsigned short)(v & 0xffffu);
    }
    __syncthreads();
    int d = t >> 1, half = t & 1;
    int n = b*128 + d;
    float acc[28];
    #pragma unroll
    for (int k = 0; k < 28; k++) acc[k] = 0.f;
    int hEnd = hist[d];
    int hBeg = (d == 0) ? 0 : hist[d - 1];
    if (n < N_NODES){
        for (int i = hBeg + half; i < hEnd; i += 2){
            int src = sorted[i];
            const float4* r = (const float4*)(z + (size_t)src*28);
            #pragma unroll
            for (int q = 0; q < 7; q++){
                float4 f = r[q];
                acc[4*q+0] += f.x; acc[4*q+1] += f.y;
                acc[4*q+2] += f.z; acc[4*q+3] += f.w;
            }
        }
    }
    #pragma unroll
    for (int k = 0; k < 28; k++) acc[k] += __shfl_xor(acc[k], 1);
    if (half == 0 && n < N_NODES){
        const float4* self = (const float4*)(z + (size_t)n*28);
        float dv = dinv[n];
        float4* o = (float4*)(out + (size_t)n*28);
        #pragma unroll
        for (int q = 0; q < 7; q++){
            float4 sv = self[q];
            o[q] = make_float4(fmaxf((acc[4*q+0]+sv.x)*dv, 0.f),
                               fmaxf((acc[4*q+1]+sv.y)*dv, 0.f),
                               fmaxf((acc[4*q+2]+sv.z)*dv, 0.f),
                               fmaxf((acc[4*q+3]+sv.w)*dv, 0.f));
        }
    }
}

// ---------- quantum features: one wave per node, DPP reductions ----------
__global__ __launch_bounds__(256) void k_feat(const float* __restrict__ x,
        const float* __restrict__ dinv, const float4* __restrict__ cmat,
        float* __restrict__ z){
    int wave = threadIdx.x >> 6;
    int lane = threadIdx.x & 63;
    int n = blockIdx.x*4 + wave;
    const float4 v = ((const float4*)(x + (size_t)n*256))[lane];
    float persq = v.x*v.x + v.y*v.y + v.z*v.z + v.w*v.w;

    float red[15];
    red[0] = persq;
    red[1] = v.x*v.x + v.y*v.y;        // S0 qubit6 (register-local)
    red[2] = v.x*v.z + v.y*v.w;        // X qubit6 (register-local)
    // lane-bit j <-> qubit 5-j. X partial = dot(v, partner v); S0 partial = masked persq.
    {   // j=0: xor mask 1 via DPP quad_perm (VALU pipe)
        float px = dpp_mov<DPP_XOR1>(v.x), py = dpp_mov<DPP_XOR1>(v.y);
        float pz = dpp_mov<DPP_XOR1>(v.z), pw = dpp_mov<DPP_XOR1>(v.w);
        red[3] = v.x*px + v.y*py + v.z*pz + v.w*pw;
        red[9] = (lane & 1) ? 0.f : persq;
    }
    {   // j=1: xor mask 2 via DPP quad_perm
        float px = dpp_mov<DPP_XOR2>(v.x), py = dpp_mov<DPP_XOR2>(v.y);
        float pz = dpp_mov<DPP_XOR2>(v.z), pw = dpp_mov<DPP_XOR2>(v.w);
        red[4] = v.x*px + v.y*py + v.z*pz + v.w*pw;
        red[10] = (lane & 2) ? 0.f : persq;
    }
    #pragma unroll
    for (int j = 2; j < 6; j++){
        float px = __shfl_xor(v.x, 1 << j), py = __shfl_xor(v.y, 1 << j);
        float pz = __shfl_xor(v.z, 1 << j), pw = __shfl_xor(v.w, 1 << j);
        red[3 + j] = v.x*px + v.y*py + v.z*pz + v.w*pw;   // 2*X (qubit 5-j)
        red[9 + j] = ((lane >> j) & 1) ? 0.0f : persq;    // S0 (qubit 5-j)
    }
    // VALU-pipe wave reductions; totals -> SGPR floats
    float S[15];
    #pragma unroll
    for (int k = 0; k < 15; k++) S[k] = lane63(wave_sum_dpp(red[k]));

    if (lane < 28){
        float4 cm = cmat[lane];
        int ap = (int)cm.w;
        // S0[a]: a==6 -> S[1]; else S[14-a].  X[a]: a==6 -> S[2]; else 0.5*S[8-a].
        float S0a = (ap==6) ? S[1] :
                    (ap==0 ? S[14] : ap==1 ? S[13] : ap==2 ? S[12] :
                     ap==3 ? S[11] : ap==4 ? S[10] : S[9]);
        float Xa  = (ap==6) ? S[2] :
                    0.5f*(ap==0 ? S[8] : ap==1 ? S[7] : ap==2 ? S[6] :
                          ap==3 ? S[5] : ap==4 ? S[4] : S[3]);
        float feat = cm.x + (cm.y*S0a + cm.z*Xa) / S[0];
        z[(size_t)n*28 + lane] = dinv[n] * feat;
    }
}

// ---------- Gram ----------
__global__ __launch_bounds__(256) void k_gram(const float* __restrict__ out, float* __restrict__ G){
    __shared__ float buf[64*28];
    int tid = threadIdx.x;
    int e[4]; int ii[4], jj[4]; bool val[4];
    #pragma unroll
    for (int k = 0; k < 4; k++){
        e[k] = tid + 256*k;
        val[k] = e[k] < 784;
        int ee = val[k] ? e[k] : 0;
        ii[k] = ee / 28; jj[k] = ee - 28*ii[k];
    }
    float acc[4] = {0.f, 0.f, 0.f, 0.f};
    int nchunks = (N_NODES + 63) / 64;
    for (int ch = blockIdx.x; ch < nchunks; ch += gridDim.x){
        int base = ch * 64;
        int total = (N_NODES - base < 64 ? N_NODES - base : 64) * 28;
        __syncthreads();
        for (int t = tid; t < 64*28; t += 256)
            buf[t] = (t < total) ? out[(size_t)base*28 + t] : 0.f;
        __syncthreads();
        for (int n = 0; n < 64; n++){
            const float* r = buf + n*28;
            #pragma unroll
            for (int k = 0; k < 4; k++) acc[k] += r[ii[k]] * r[jj[k]];
        }
    }
    #pragma unroll
    for (int k = 0; k < 4; k++) if (val[k]) atomicAdd(&G[e[k]], acc[k]);
}

// ---------- MLP ----------
__global__ __launch_bounds__(256) void k_mlp1(const float* __restrict__ G,
        const float* __restrict__ W1, const float* __restrict__ b1, float* __restrict__ h){
    int j = blockIdx.x;
    const float* w = W1 + (size_t)j*784;
    float s = 0.f;
    for (int i = threadIdx.x; i < 784; i += 256) s += G[i] * w[i];
    __shared__ float sh[256];
    sh[threadIdx.x] = s; __syncthreads();
    for (int ofs = 128; ofs > 0; ofs >>= 1){
        if (threadIdx.x < ofs) sh[threadIdx.x] += sh[threadIdx.x + ofs];
        __syncthreads();
    }
    if (threadIdx.x == 0) h[j] = fmaxf(sh[0] + b1[j], 0.f);
}

__global__ void k_mlp2(const float* __restrict__ h, const float* __restrict__ W2,
        const float* __restrict__ b2, float* __restrict__ outp){
    __shared__ float sh[128];
    int t = threadIdx.x;
    sh[t] = h[t] * W2[t];
    __syncthreads();
    for (int ofs = 64; ofs > 0; ofs >>= 1){
        if (t < ofs) sh[t] += sh[t + ofs];
        __syncthreads();
    }
    if (t == 0) outp[0] = 1.f / (1.f + expf(-(sh[0] + b2[0])));
}

extern "C" void kernel_launch(void* const* d_in, const int* in_sizes, int n_in,
                              void* d_out, int out_size, void* d_ws, size_t ws_size,
                              hipStream_t stream){
    const float* x  = (const float*)d_in[0];
    const void*  ei = d_in[1];
    const float* qw = (const float*)d_in[2];
    const float* W1 = (const float*)d_in[3];
    const float* b1 = (const float*)d_in[4];
    const float* W2 = (const float*)d_in[5];
    const float* b2 = (const float*)d_in[6];
    float* outp = (float*)d_out;

    char* base = (char*)d_ws;
    float*    z     = (float*)base;    base += (size_t)N_NODES*28*4;
    float*    ob    = (float*)base;    base += (size_t)N_NODES*28*4;
    unsigned* pairs = (unsigned*)base; base += (size_t)N_EDGES*4;
    float*    dinv  = (float*)base;    base += (size_t)N_NODES*4;
    int*      chunkCnt    = (int*)base; base += (size_t)NB_BUCKETS*NCHUNK*4;
    int*      bucketCnt   = (int*)base; base += 2048;
    int*      bucketStart = (int*)base; base += 2048;
    float4*   cmat  = (float4*)base;   base += 448;
    float*    G     = (float*)base;    base += 784*4;
    float*    h     = (float*)base;    base += 512;
    int*      flag  = (int*)base;      base += 16;

    hipMemsetAsync(G, 0, 784*4, stream);

    k_probe<<<1, 64, 0, stream>>>(ei, flag);
    k_pairs<<<1, 32, 0, stream>>>(qw, cmat);
    k_part1<<<NCHUNK, 256, 0, stream>>>(ei, flag, chunkCnt);
    k_chunkscan<<<NB_BUCKETS, 256, 0, stream>>>(chunkCnt, bucketCnt);
    k_scanb<<<1, 256, 0, stream>>>(bucketCnt, bucketStart);
    k_part2<<<NCHUNK, 256, 0, stream>>>(ei, flag, chunkCnt, bucketStart, pairs);
    k_deg<<<NB_BUCKETS, 256, 0, stream>>>(pairs, bucketStart, dinv);
    k_feat<<<N_NODES/4, 256, 0, stream>>>(x, dinv, cmat, z);
    k_gs<<<NB_BUCKETS, 256, 0, stream>>>(pairs, bucketStart, z, dinv, ob);
    k_gram<<<196, 256, 0, stream>>>(ob, G);
    k_mlp1<<<128, 256, 0, stream>>>(G, W1, b1, h);
    k_mlp2<<<1, 128, 0, stream>>>(h, W2, b2, outp);
}

// Round 5
// 237.197 us; speedup vs baseline: 1.6765x; 1.0279x over previous
//
#include <hip/hip_runtime.h>
#include <math.h>

#define N_NODES 50000
#define N_EDGES 1600000
#define NB_BUCKETS 391      // ceil(50000/128), bucket = dst>>7
#define PART_CHUNK 8192
#define NCHUNK 196          // ceil(N_EDGES / PART_CHUNK)
#define GS_CAP 6144
#define ZSTRIDE 32          // z row padded to 128B for aligned 2-line gathers

// ---------- DPP helpers (VALU-pipe cross-lane, no LDS) ----------
template<int CTRL>
__device__ inline float dpp_mov(float x){
    return __int_as_float(__builtin_amdgcn_update_dpp(0, __float_as_int(x), CTRL, 0xf, 0xf, false));
}
__device__ inline float wave_sum_dpp(float x){
    x += dpp_mov<0x111>(x);   // row_shr:1
    x += dpp_mov<0x112>(x);   // row_shr:2
    x += dpp_mov<0x114>(x);   // row_shr:4
    x += dpp_mov<0x118>(x);   // row_shr:8
    x += dpp_mov<0x142>(x);   // row_bcast:15
    x += dpp_mov<0x143>(x);   // row_bcast:31
    return x;
}
__device__ inline float lane63(float x){
    return __int_as_float(__builtin_amdgcn_readlane(__float_as_int(x), 63));
}
#define DPP_XOR1 0xB1   // quad_perm [1,0,3,2]
#define DPP_XOR2 0x4E   // quad_perm [2,3,0,1]

// ---------- complex 2x2 helpers ----------
struct C2 { float x, y; };
__device__ inline C2 mkc(float x, float y){ C2 r; r.x=x; r.y=y; return r; }
__device__ inline C2 cmul(C2 a, C2 b){ return mkc(a.x*b.x - a.y*b.y, a.x*b.y + a.y*b.x); }
__device__ inline C2 cadd(C2 a, C2 b){ return mkc(a.x+b.x, a.y+b.y); }

// ---------- per-pair observable B = A^dag Z A folded into feature coeffs ----------
__global__ void k_pairs(const float* __restrict__ qw, float4* __restrict__ cmat){
    int p = blockIdx.x*blockDim.x + threadIdx.x;
    if (p >= 28) return;
    int a = 0; { int rem = p, q = 0; while (rem >= 7 - q){ rem -= 7 - q; q++; } a = q; }
    C2 M00 = mkc(1,0), M01 = mkc(0,0), M10 = mkc(0,0), M11 = mkc(1,0);
    for (int k = 0; k < 6; k++){
        float th = 0.5f * qw[p*6 + k];
        float s, c; sincosf(th, &s, &c);
        C2 R00, R01, R10, R11;
        int type = k % 3;
        if (type == 0){      // Rx
            R00 = mkc(c,0); R01 = mkc(0,-s); R10 = mkc(0,-s); R11 = mkc(c,0);
        } else if (type == 1){ // Ry
            R00 = mkc(c,0); R01 = mkc(-s,0); R10 = mkc(s,0); R11 = mkc(c,0);
        } else {             // Rz
            R00 = mkc(c,-s); R01 = mkc(0,0); R10 = mkc(0,0); R11 = mkc(c,s);
        }
        C2 N00 = cadd(cmul(R00,M00), cmul(R01,M10));
        C2 N01 = cadd(cmul(R00,M01), cmul(R01,M11));
        C2 N10 = cadd(cmul(R10,M00), cmul(R11,M10));
        C2 N11 = cadd(cmul(R10,M01), cmul(R11,M11));
        M00=N00; M01=N01; M10=N10; M11=N11;
    }
    float B00  = (M00.x*M00.x + M00.y*M00.y) - (M10.x*M10.x + M10.y*M10.y);
    float B11  = (M01.x*M01.x + M01.y*M01.y) - (M11.x*M11.x + M11.y*M11.y);
    float B01r = (M00.x*M01.x + M00.y*M01.y) - (M10.x*M11.x + M10.y*M11.y);
    cmat[p] = make_float4(0.5f + 0.5f*B11, 0.5f*(B00 - B11), B01r, (float)a);
}

// ---------- edge dtype probe ----------
__global__ void k_probe(const void* __restrict__ ei, int* __restrict__ flag){
    if (threadIdx.x == 0 && blockIdx.x == 0){
        const long long* e64 = (const long long*)ei;
        int ok = 1;
        for (int i = 0; i < 64; i++){
            long long v = e64[i];
            if (v < 0 || v >= N_NODES) ok = 0;
        }
        flag[0] = ok;
    }
}

__device__ inline int get_edge(const void* ei, int is64, long long idx){
    if (is64) return (int)((const long long*)ei)[idx];
    return ((const int*)ei)[idx];
}

// ---------- pass 1: per-chunk bucket histogram ----------
__global__ __launch_bounds__(256) void k_part1(const void* __restrict__ ei,
        const int* __restrict__ flag, int* __restrict__ chunkCnt){
    __shared__ int hist[NB_BUCKETS];
    int tid = threadIdx.x, c = blockIdx.x;
    long long base = (long long)c * PART_CHUNK;
    int cnt = (int)((N_EDGES - base < PART_CHUNK) ? (N_EDGES - base) : PART_CHUNK);
    for (int i = tid; i < NB_BUCKETS; i += 256) hist[i] = 0;
    __syncthreads();
    int is64 = flag[0];
    for (int i = tid; i < cnt; i += 256){
        int dst = get_edge(ei, is64, (long long)N_EDGES + base + i);
        atomicAdd(&hist[dst >> 7], 1);
    }
    __syncthreads();
    for (int i = tid; i < NB_BUCKETS; i += 256)
        chunkCnt[i*NCHUNK + c] = hist[i];
}

// ---------- per-bucket exclusive scan over chunks (in place) + bucket totals ----------
__global__ __launch_bounds__(256) void k_chunkscan(int* __restrict__ chunkCnt,
        int* __restrict__ bucketCnt){
    __shared__ int sh[256];
    int b = blockIdx.x, t = threadIdx.x;
    int v = (t < NCHUNK) ? chunkCnt[b*NCHUNK + t] : 0;
    sh[t] = v; __syncthreads();
    for (int ofs = 1; ofs < 256; ofs <<= 1){
        int u = (t >= ofs) ? sh[t - ofs] : 0; __syncthreads();
        sh[t] += u; __syncthreads();
    }
    if (t < NCHUNK) chunkCnt[b*NCHUNK + t] = sh[t] - v;  // exclusive
    if (t == 255) bucketCnt[b] = sh[255];
}

// ---------- exclusive scan of bucket counts (one block) ----------
__global__ __launch_bounds__(256) void k_scanb(const int* __restrict__ bucketCnt,
        int* __restrict__ bucketStart){
    __shared__ int sh[NB_BUCKETS];
    int t = threadIdx.x;
    for (int i = t; i < NB_BUCKETS; i += 256) sh[i] = bucketCnt[i];
    __syncthreads();
    for (int ofs = 1; ofs < NB_BUCKETS; ofs <<= 1){
        int i0 = t, i1 = t + 256;
        bool a0 = i0 < NB_BUCKETS, a1 = i1 < NB_BUCKETS;
        int v0 = 0, v1 = 0;
        if (a0) v0 = sh[i0] + (i0 >= ofs ? sh[i0 - ofs] : 0);
        if (a1) v1 = sh[i1] + (i1 >= ofs ? sh[i1 - ofs] : 0);
        __syncthreads();
        if (a0) sh[i0] = v0;
        if (a1) sh[i1] = v1;
        __syncthreads();
    }
    for (int i = t; i < NB_BUCKETS; i += 256) bucketStart[i + 1] = sh[i];
    if (t == 0) bucketStart[0] = 0;
}

// ---------- pass 2: LDS bucket-sort chunk, deterministic dense copy-out ----------
__global__ __launch_bounds__(256) void k_part2(const void* __restrict__ ei,
        const int* __restrict__ flag, const int* __restrict__ chunkCnt,
        const int* __restrict__ bucketStart, unsigned* __restrict__ pairs){
    __shared__ int hist[NB_BUCKETS];
    __shared__ int cntb[NB_BUCKETS];
    __shared__ int cursor[NB_BUCKETS];
    __shared__ int copyBase[NB_BUCKETS];
    __shared__ unsigned sorted[PART_CHUNK];
    int tid = threadIdx.x, c = blockIdx.x;
    long long base = (long long)c * PART_CHUNK;
    int cnt = (int)((N_EDGES - base < PART_CHUNK) ? (N_EDGES - base) : PART_CHUNK);
    for (int i = tid; i < NB_BUCKETS; i += 256) hist[i] = 0;
    __syncthreads();
    int is64 = flag[0];
    for (int i = tid; i < cnt; i += 256){
        int dst = get_edge(ei, is64, (long long)N_EDGES + base + i);
        atomicAdd(&hist[dst >> 7], 1);
    }
    __syncthreads();
    for (int i = tid; i < NB_BUCKETS; i += 256) cntb[i] = hist[i];
    __syncthreads();
    for (int ofs = 1; ofs < NB_BUCKETS; ofs <<= 1){
        int i0 = tid, i1 = tid + 256;
        bool a0 = i0 < NB_BUCKETS, a1 = i1 < NB_BUCKETS;
        int v0 = 0, v1 = 0;
        if (a0) v0 = hist[i0] + (i0 >= ofs ? hist[i0 - ofs] : 0);
        if (a1) v1 = hist[i1] + (i1 >= ofs ? hist[i1 - ofs] : 0);
        __syncthreads();
        if (a0) hist[i0] = v0;
        if (a1) hist[i1] = v1;
        __syncthreads();
    }
    for (int i = tid; i < NB_BUCKETS; i += 256){
        int ls = hist[i] - cntb[i];
        int gbase = bucketStart[i] + chunkCnt[i*NCHUNK + c];
        copyBase[i] = gbase - ls;
        cursor[i] = ls;
    }
    __syncthreads();
    for (int i = tid; i < cnt; i += 256){
        int src = get_edge(ei, is64, base + i);
        int dst = get_edge(ei, is64, (long long)N_EDGES + base + i);
        int pos = atomicAdd(&cursor[dst >> 7], 1);
        sorted[pos] = ((unsigned)dst << 16) | (unsigned)src;
    }
    __syncthreads();
    for (int i = tid; i < cnt; i += 256){
        unsigned v = sorted[i];
        int b = (int)(v >> 23);
        pairs[copyBase[b] + i] = v;
    }
}

// ---------- per-bucket counting sort -> ushort CSR + nodeOff + dinv ----------
__global__ __launch_bounds__(256) void k_sort(const unsigned* __restrict__ pairs,
        const int* __restrict__ bucketStart, unsigned short* __restrict__ csr,
        int* __restrict__ nodeOff, float* __restrict__ dinv){
    __shared__ unsigned short sorted[GS_CAP];
    __shared__ int hist[128];
    __shared__ int cursor[128];
    int b = blockIdx.x, t = threadIdx.x;
    int s0 = bucketStart[b];
    int cnt = bucketStart[b + 1] - s0;
    if (cnt > GS_CAP) cnt = GS_CAP;
    if (t < 128) hist[t] = 0;
    __syncthreads();
    for (int i = t; i < cnt; i += 256){
        unsigned v = pairs[s0 + i];
        atomicAdd(&hist[(v >> 16) & 127], 1);
    }
    __syncthreads();
    int mycnt = (t < 128) ? hist[t] : 0;
    for (int ofs = 1; ofs < 128; ofs <<= 1){
        int nv = 0;
        if (t < 128) nv = hist[t] + (t >= ofs ? hist[t - ofs] : 0);
        __syncthreads();
        if (t < 128) hist[t] = nv;
        __syncthreads();
    }
    if (t < 128){
        cursor[t] = hist[t] - mycnt;               // exclusive start
        int n = b*128 + t;
        if (n < N_NODES){
            nodeOff[n] = s0 + hist[t] - mycnt;     // globally monotone
            dinv[n] = rsqrtf((float)(mycnt + 1));
        }
    }
    __syncthreads();
    for (int i = t; i < cnt; i += 256){
        unsigned v = pairs[s0 + i];
        int d = (v >> 16) & 127;
        int pos = atomicAdd(&cursor[d], 1);
        sorted[pos] = (unsigned short)(v & 0xffffu);
    }
    __syncthreads();
    for (int i = t; i < cnt; i += 256) csr[s0 + i] = sorted[i];
}

// ---------- GCN aggregate + relu: 8 threads per node, CSR gather ----------
__global__ __launch_bounds__(256) void k_gather(const unsigned short* __restrict__ csr,
        const int* __restrict__ nodeOff, const float* __restrict__ z,
        const float* __restrict__ dinv, float* __restrict__ out){
    int g = blockIdx.x*256 + threadIdx.x;
    int n = g >> 3, sub = g & 7;
    if (n >= N_NODES) return;
    int beg = nodeOff[n];
    int end = (n == N_NODES - 1) ? N_EDGES : nodeOff[n + 1];
    float acc[28];
    #pragma unroll
    for (int k = 0; k < 28; k++) acc[k] = 0.f;
    for (int i = beg + sub; i < end; i += 8){
        int src = csr[i];
        const float4* r = (const float4*)(z + (size_t)src*ZSTRIDE);
        #pragma unroll
        for (int q = 0; q < 7; q++){
            float4 f = r[q];
            acc[4*q+0] += f.x; acc[4*q+1] += f.y;
            acc[4*q+2] += f.z; acc[4*q+3] += f.w;
        }
    }
    #pragma unroll
    for (int k = 0; k < 28; k++){
        acc[k] += __shfl_xor(acc[k], 1);
        acc[k] += __shfl_xor(acc[k], 2);
        acc[k] += __shfl_xor(acc[k], 4);
    }
    if (sub == 0){
        const float4* self = (const float4*)(z + (size_t)n*ZSTRIDE);
        float dv = dinv[n];
        float4* o = (float4*)(out + (size_t)n*28);
        #pragma unroll
        for (int q = 0; q < 7; q++){
            float4 sv = self[q];
            o[q] = make_float4(fmaxf((acc[4*q+0]+sv.x)*dv, 0.f),
                               fmaxf((acc[4*q+1]+sv.y)*dv, 0.f),
                               fmaxf((acc[4*q+2]+sv.z)*dv, 0.f),
                               fmaxf((acc[4*q+3]+sv.w)*dv, 0.f));
        }
    }
}

// ---------- quantum features: one wave per node, DPP reductions ----------
__global__ __launch_bounds__(256) void k_feat(const float* __restrict__ x,
        const float* __restrict__ dinv, const float4* __restrict__ cmat,
        float* __restrict__ z){
    int wave = threadIdx.x >> 6;
    int lane = threadIdx.x & 63;
    int n = blockIdx.x*4 + wave;
    const float4 v = ((const float4*)(x + (size_t)n*256))[lane];
    float persq = v.x*v.x + v.y*v.y + v.z*v.z + v.w*v.w;

    float red[15];
    red[0] = persq;
    red[1] = v.x*v.x + v.y*v.y;        // S0 qubit6
    red[2] = v.x*v.z + v.y*v.w;        // X qubit6
    {   // j=0: xor mask 1 via DPP quad_perm
        float px = dpp_mov<DPP_XOR1>(v.x), py = dpp_mov<DPP_XOR1>(v.y);
        float pz = dpp_mov<DPP_XOR1>(v.z), pw = dpp_mov<DPP_XOR1>(v.w);
        red[3] = v.x*px + v.y*py + v.z*pz + v.w*pw;
        red[9] = (lane & 1) ? 0.f : persq;
    }
    {   // j=1: xor mask 2 via DPP quad_perm
        float px = dpp_mov<DPP_XOR2>(v.x), py = dpp_mov<DPP_XOR2>(v.y);
        float pz = dpp_mov<DPP_XOR2>(v.z), pw = dpp_mov<DPP_XOR2>(v.w);
        red[4] = v.x*px + v.y*py + v.z*pz + v.w*pw;
        red[10] = (lane & 2) ? 0.f : persq;
    }
    #pragma unroll
    for (int j = 2; j < 6; j++){
        float px = __shfl_xor(v.x, 1 << j), py = __shfl_xor(v.y, 1 << j);
        float pz = __shfl_xor(v.z, 1 << j), pw = __shfl_xor(v.w, 1 << j);
        red[3 + j] = v.x*px + v.y*py + v.z*pz + v.w*pw;
        red[9 + j] = ((lane >> j) & 1) ? 0.0f : persq;
    }
    float S[15];
    #pragma unroll
    for (int k = 0; k < 15; k++) S[k] = lane63(wave_sum_dpp(red[k]));

    if (lane < 28){
        float4 cm = cmat[lane];
        int ap = (int)cm.w;
        float S0a = (ap==6) ? S[1] :
                    (ap==0 ? S[14] : ap==1 ? S[13] : ap==2 ? S[12] :
                     ap==3 ? S[11] : ap==4 ? S[10] : S[9]);
        float Xa  = (ap==6) ? S[2] :
                    0.5f*(ap==0 ? S[8] : ap==1 ? S[7] : ap==2 ? S[6] :
                          ap==3 ? S[5] : ap==4 ? S[4] : S[3]);
        float feat = cm.x + (cm.y*S0a + cm.z*Xa) / S[0];
        z[(size_t)n*ZSTRIDE + lane] = dinv[n] * feat;
    }
}

// ---------- Gram ----------
__global__ __launch_bounds__(256) void k_gram(const float* __restrict__ out, float* __restrict__ G){
    __shared__ float buf[64*28];
    int tid = threadIdx.x;
    int e[4]; int ii[4], jj[4]; bool val[4];
    #pragma unroll
    for (int k = 0; k < 4; k++){
        e[k] = tid + 256*k;
        val[k] = e[k] < 784;
        int ee = val[k] ? e[k] : 0;
        ii[k] = ee / 28; jj[k] = ee - 28*ii[k];
    }
    float acc[4] = {0.f, 0.f, 0.f, 0.f};
    int nchunks = (N_NODES + 63) / 64;
    for (int ch = blockIdx.x; ch < nchunks; ch += gridDim.x){
        int base = ch * 64;
        int total = (N_NODES - base < 64 ? N_NODES - base : 64) * 28;
        __syncthreads();
        for (int t = tid; t < 64*28; t += 256)
            buf[t] = (t < total) ? out[(size_t)base*28 + t] : 0.f;
        __syncthreads();
        for (int n = 0; n < 64; n++){
            const float* r = buf + n*28;
            #pragma unroll
            for (int k = 0; k < 4; k++) acc[k] += r[ii[k]] * r[jj[k]];
        }
    }
    #pragma unroll
    for (int k = 0; k < 4; k++) if (val[k]) atomicAdd(&G[e[k]], acc[k]);
}

// ---------- MLP ----------
__global__ __launch_bounds__(256) void k_mlp1(const float* __restrict__ G,
        const float* __restrict__ W1, const float* __restrict__ b1, float* __restrict__ h){
    int j = blockIdx.x;
    const float* w = W1 + (size_t)j*784;
    float s = 0.f;
    for (int i = threadIdx.x; i < 784; i += 256) s += G[i] * w[i];
    __shared__ float sh[256];
    sh[threadIdx.x] = s; __syncthreads();
    for (int ofs = 128; ofs > 0; ofs >>= 1){
        if (threadIdx.x < ofs) sh[threadIdx.x] += sh[threadIdx.x + ofs];
        __syncthreads();
    }
    if (threadIdx.x == 0) h[j] = fmaxf(sh[0] + b1[j], 0.f);
}

__global__ void k_mlp2(const float* __restrict__ h, const float* __restrict__ W2,
        const float* __restrict__ b2, float* __restrict__ outp){
    __shared__ float sh[128];
    int t = threadIdx.x;
    sh[t] = h[t] * W2[t];
    __syncthreads();
    for (int ofs = 64; ofs > 0; ofs >>= 1){
        if (t < ofs) sh[t] += sh[t + ofs];
        __syncthreads();
    }
    if (t == 0) outp[0] = 1.f / (1.f + expf(-(sh[0] + b2[0])));
}

extern "C" void kernel_launch(void* const* d_in, const int* in_sizes, int n_in,
                              void* d_out, int out_size, void* d_ws, size_t ws_size,
                              hipStream_t stream){
    const float* x  = (const float*)d_in[0];
    const void*  ei = d_in[1];
    const float* qw = (const float*)d_in[2];
    const float* W1 = (const float*)d_in[3];
    const float* b1 = (const float*)d_in[4];
    const float* W2 = (const float*)d_in[5];
    const float* b2 = (const float*)d_in[6];
    float* outp = (float*)d_out;

    char* base = (char*)d_ws;
    float*          z     = (float*)base;          base += (size_t)N_NODES*ZSTRIDE*4;
    float*          ob    = (float*)base;          base += (size_t)N_NODES*28*4;
    unsigned*       pairs = (unsigned*)base;       base += (size_t)N_EDGES*4;
    unsigned short* csr   = (unsigned short*)base; base += (size_t)N_EDGES*2;
    int*            nodeOff = (int*)base;          base += (size_t)N_NODES*4;
    float*          dinv  = (float*)base;          base += (size_t)N_NODES*4;
    int*            chunkCnt    = (int*)base;      base += (size_t)NB_BUCKETS*NCHUNK*4;
    int*            bucketCnt   = (int*)base;      base += 2048;
    int*            bucketStart = (int*)base;      base += 2048;
    float4*         cmat  = (float4*)base;         base += 448;
    float*          G     = (float*)base;          base += 784*4;
    float*          h     = (float*)base;          base += 512;
    int*            flag  = (int*)base;            base += 16;

    hipMemsetAsync(G, 0, 784*4, stream);

    k_probe<<<1, 64, 0, stream>>>(ei, flag);
    k_pairs<<<1, 32, 0, stream>>>(qw, cmat);
    k_part1<<<NCHUNK, 256, 0, stream>>>(ei, flag, chunkCnt);
    k_chunkscan<<<NB_BUCKETS, 256, 0, stream>>>(chunkCnt, bucketCnt);
    k_scanb<<<1, 256, 0, stream>>>(bucketCnt, bucketStart);
    k_part2<<<NCHUNK, 256, 0, stream>>>(ei, flag, chunkCnt, bucketStart, pairs);
    k_sort<<<NB_BUCKETS, 256, 0, stream>>>(pairs, bucketStart, csr, nodeOff, dinv);
    k_feat<<<N_NODES/4, 256, 0, stream>>>(x, dinv, cmat, z);
    k_gather<<<(N_NODES*8 + 255)/256, 256, 0, stream>>>(csr, nodeOff, z, dinv, ob);
    k_gram<<<196, 256, 0, stream>>>(ob, G);
    k_mlp1<<<128, 256, 0, stream>>>(G, W1, b1, h);
    k_mlp2<<<1, 128, 0, stream>>>(h, W2, b2, outp);
}

// Round 6
// 233.506 us; speedup vs baseline: 1.7030x; 1.0158x over previous
//
#include <hip/hip_runtime.h>
#include <hip/hip_fp16.h>
#include <math.h>

#define N_NODES 50000
#define N_EDGES 1600000
#define NB_BUCKETS 391      // ceil(50000/128), bucket = dst>>7
#define NB_PAD 392
#define PART_CHUNK 8192
#define NCHUNK 196          // ceil(N_EDGES / PART_CHUNK)
#define GS_CAP 6144
#define ZSTRIDE 32          // z row = 32 halves = 64B, one cache line

// ---------- DPP helpers (VALU-pipe cross-lane, no LDS) ----------
template<int CTRL>
__device__ inline float dpp_mov(float x){
    return __int_as_float(__builtin_amdgcn_update_dpp(0, __float_as_int(x), CTRL, 0xf, 0xf, false));
}
__device__ inline float wave_sum_dpp(float x){
    x += dpp_mov<0x111>(x);   // row_shr:1
    x += dpp_mov<0x112>(x);   // row_shr:2
    x += dpp_mov<0x114>(x);   // row_shr:4
    x += dpp_mov<0x118>(x);   // row_shr:8
    x += dpp_mov<0x142>(x);   // row_bcast:15
    x += dpp_mov<0x143>(x);   // row_bcast:31
    return x;
}
__device__ inline float lane63(float x){
    return __int_as_float(__builtin_amdgcn_readlane(__float_as_int(x), 63));
}
#define DPP_XOR1 0xB1   // quad_perm [1,0,3,2]
#define DPP_XOR2 0x4E   // quad_perm [2,3,0,1]

// ---------- complex 2x2 helpers ----------
struct C2 { float x, y; };
__device__ inline C2 mkc(float x, float y){ C2 r; r.x=x; r.y=y; return r; }
__device__ inline C2 cmul(C2 a, C2 b){ return mkc(a.x*b.x - a.y*b.y, a.x*b.y + a.y*b.x); }
__device__ inline C2 cadd(C2 a, C2 b){ return mkc(a.x+b.x, a.y+b.y); }

// ---------- K0: probe edge dtype + per-pair observable coefficients ----------
__global__ void k_init(const float* __restrict__ qw, const void* __restrict__ ei,
        float4* __restrict__ cmat, int* __restrict__ flag){
    int t = threadIdx.x;
    if (t == 63){
        const long long* e64 = (const long long*)ei;
        int ok = 1;
        for (int i = 0; i < 64; i++){
            long long v = e64[i];
            if (v < 0 || v >= N_NODES) ok = 0;
        }
        flag[0] = ok;
    }
    if (t < 28){
        int p = t;
        int a = 0; { int rem = p, q = 0; while (rem >= 7 - q){ rem -= 7 - q; q++; } a = q; }
        C2 M00 = mkc(1,0), M01 = mkc(0,0), M10 = mkc(0,0), M11 = mkc(1,0);
        for (int k = 0; k < 6; k++){
            float th = 0.5f * qw[p*6 + k];
            float s, c; sincosf(th, &s, &c);
            C2 R00, R01, R10, R11;
            int type = k % 3;
            if (type == 0){      // Rx
                R00 = mkc(c,0); R01 = mkc(0,-s); R10 = mkc(0,-s); R11 = mkc(c,0);
            } else if (type == 1){ // Ry
                R00 = mkc(c,0); R01 = mkc(-s,0); R10 = mkc(s,0); R11 = mkc(c,0);
            } else {             // Rz
                R00 = mkc(c,-s); R01 = mkc(0,0); R10 = mkc(0,0); R11 = mkc(c,s);
            }
            C2 N00 = cadd(cmul(R00,M00), cmul(R01,M10));
            C2 N01 = cadd(cmul(R00,M01), cmul(R01,M11));
            C2 N10 = cadd(cmul(R10,M00), cmul(R11,M10));
            C2 N11 = cadd(cmul(R10,M01), cmul(R11,M11));
            M00=N00; M01=N01; M10=N10; M11=N11;
        }
        float B00  = (M00.x*M00.x + M00.y*M00.y) - (M10.x*M10.x + M10.y*M10.y);
        float B11  = (M01.x*M01.x + M01.y*M01.y) - (M11.x*M11.x + M11.y*M11.y);
        float B01r = (M00.x*M01.x + M00.y*M01.y) - (M10.x*M11.x + M10.y*M11.y);
        cmat[p] = make_float4(0.5f + 0.5f*B11, 0.5f*(B00 - B11), B01r, (float)a);
    }
}

__device__ inline int get_edge(const void* ei, int is64, long long idx){
    if (is64) return (int)((const long long*)ei)[idx];
    return ((const int*)ei)[idx];
}

// ---------- pass 1: per-chunk bucket histogram; also zero G ----------
__global__ __launch_bounds__(256) void k_part1(const void* __restrict__ ei,
        const int* __restrict__ flag, int* __restrict__ chunkCnt,
        int* __restrict__ rawCnt, float* __restrict__ G){
    __shared__ int hist[NB_BUCKETS];
    int tid = threadIdx.x, c = blockIdx.x;
    if (c == 0){ for (int i = tid; i < 784; i += 256) G[i] = 0.f; }
    long long base = (long long)c * PART_CHUNK;
    int cnt = (int)((N_EDGES - base < PART_CHUNK) ? (N_EDGES - base) : PART_CHUNK);
    for (int i = tid; i < NB_BUCKETS; i += 256) hist[i] = 0;
    __syncthreads();
    int is64 = flag[0];
    for (int i = tid; i < cnt; i += 256){
        int dst = get_edge(ei, is64, (long long)N_EDGES + base + i);
        atomicAdd(&hist[dst >> 7], 1);
    }
    __syncthreads();
    for (int i = tid; i < NB_BUCKETS; i += 256){
        int h = hist[i];
        chunkCnt[i*NCHUNK + c] = h;      // layout for per-bucket chunk scan
        rawCnt[c*NB_PAD + i]   = h;      // layout for part2 row reload
    }
}

// ---------- per-bucket exclusive scan over chunks (in place) + bucket totals ----------
__global__ __launch_bounds__(256) void k_chunkscan(int* __restrict__ chunkCnt,
        int* __restrict__ bucketCnt){
    __shared__ int sh[256];
    int b = blockIdx.x, t = threadIdx.x;
    int v = (t < NCHUNK) ? chunkCnt[b*NCHUNK + t] : 0;
    sh[t] = v; __syncthreads();
    for (int ofs = 1; ofs < 256; ofs <<= 1){
        int u = (t >= ofs) ? sh[t - ofs] : 0; __syncthreads();
        sh[t] += u; __syncthreads();
    }
    if (t < NCHUNK) chunkCnt[b*NCHUNK + t] = sh[t] - v;  // exclusive
    if (t == 255) bucketCnt[b] = sh[255];
}

// ---------- exclusive scan of bucket counts (one block) ----------
__global__ __launch_bounds__(256) void k_scanb(const int* __restrict__ bucketCnt,
        int* __restrict__ bucketStart){
    __shared__ int sh[NB_BUCKETS];
    int t = threadIdx.x;
    for (int i = t; i < NB_BUCKETS; i += 256) sh[i] = bucketCnt[i];
    __syncthreads();
    for (int ofs = 1; ofs < NB_BUCKETS; ofs <<= 1){
        int i0 = t, i1 = t + 256;
        bool a0 = i0 < NB_BUCKETS, a1 = i1 < NB_BUCKETS;
        int v0 = 0, v1 = 0;
        if (a0) v0 = sh[i0] + (i0 >= ofs ? sh[i0 - ofs] : 0);
        if (a1) v1 = sh[i1] + (i1 >= ofs ? sh[i1 - ofs] : 0);
        __syncthreads();
        if (a0) sh[i0] = v0;
        if (a1) sh[i1] = v1;
        __syncthreads();
    }
    for (int i = t; i < NB_BUCKETS; i += 256) bucketStart[i + 1] = sh[i];
    if (t == 0) bucketStart[0] = 0;
}

// ---------- pass 2: LDS bucket-sort chunk using precomputed counts ----------
__global__ __launch_bounds__(256) void k_part2(const void* __restrict__ ei,
        const int* __restrict__ flag, const int* __restrict__ chunkCnt,
        const int* __restrict__ rawCnt, const int* __restrict__ bucketStart,
        unsigned* __restrict__ pairs){
    __shared__ int hist[NB_BUCKETS];
    __shared__ int cntb[NB_BUCKETS];
    __shared__ int cursor[NB_BUCKETS];
    __shared__ int copyBase[NB_BUCKETS];
    __shared__ unsigned sorted[PART_CHUNK];
    int tid = threadIdx.x, c = blockIdx.x;
    long long base = (long long)c * PART_CHUNK;
    int cnt = (int)((N_EDGES - base < PART_CHUNK) ? (N_EDGES - base) : PART_CHUNK);
    for (int i = tid; i < NB_BUCKETS; i += 256){
        int h = rawCnt[c*NB_PAD + i];
        cntb[i] = h; hist[i] = h;
    }
    __syncthreads();
    for (int ofs = 1; ofs < NB_BUCKETS; ofs <<= 1){
        int i0 = tid, i1 = tid + 256;
        bool a0 = i0 < NB_BUCKETS, a1 = i1 < NB_BUCKETS;
        int v0 = 0, v1 = 0;
        if (a0) v0 = hist[i0] + (i0 >= ofs ? hist[i0 - ofs] : 0);
        if (a1) v1 = hist[i1] + (i1 >= ofs ? hist[i1 - ofs] : 0);
        __syncthreads();
        if (a0) hist[i0] = v0;
        if (a1) hist[i1] = v1;
        __syncthreads();
    }
    for (int i = tid; i < NB_BUCKETS; i += 256){
        int ls = hist[i] - cntb[i];                    // local exclusive start
        int gbase = bucketStart[i] + chunkCnt[i*NCHUNK + c];
        copyBase[i] = gbase - ls;
        cursor[i] = ls;
    }
    __syncthreads();
    int is64 = flag[0];
    for (int i = tid; i < cnt; i += 256){
        int src = get_edge(ei, is64, base + i);
        int dst = get_edge(ei, is64, (long long)N_EDGES + base + i);
        int pos = atomicAdd(&cursor[dst >> 7], 1);
        sorted[pos] = ((unsigned)dst << 16) | (unsigned)src;
    }
    __syncthreads();
    for (int i = tid; i < cnt; i += 256){
        unsigned v = sorted[i];
        int b = (int)(v >> 23);
        pairs[copyBase[b] + i] = v;
    }
}

// ---------- per-bucket counting sort -> ushort CSR + nodeOff + dinv ----------
__global__ __launch_bounds__(256) void k_sort(const unsigned* __restrict__ pairs,
        const int* __restrict__ bucketStart, unsigned short* __restrict__ csr,
        int* __restrict__ nodeOff, float* __restrict__ dinv){
    __shared__ unsigned short sorted[GS_CAP];
    __shared__ int hist[128];
    __shared__ int cursor[128];
    int b = blockIdx.x, t = threadIdx.x;
    int s0 = bucketStart[b];
    int cnt = bucketStart[b + 1] - s0;
    if (cnt > GS_CAP) cnt = GS_CAP;
    if (t < 128) hist[t] = 0;
    __syncthreads();
    for (int i = t; i < cnt; i += 256){
        unsigned v = pairs[s0 + i];
        atomicAdd(&hist[(v >> 16) & 127], 1);
    }
    __syncthreads();
    int mycnt = (t < 128) ? hist[t] : 0;
    for (int ofs = 1; ofs < 128; ofs <<= 1){
        int nv = 0;
        if (t < 128) nv = hist[t] + (t >= ofs ? hist[t - ofs] : 0);
        __syncthreads();
        if (t < 128) hist[t] = nv;
        __syncthreads();
    }
    if (t < 128){
        cursor[t] = hist[t] - mycnt;               // exclusive start
        int n = b*128 + t;
        if (n < N_NODES){
            nodeOff[n] = s0 + hist[t] - mycnt;     // globally monotone
            dinv[n] = rsqrtf((float)(mycnt + 1));
        }
    }
    __syncthreads();
    for (int i = t; i < cnt; i += 256){
        unsigned v = pairs[s0 + i];
        int d = (v >> 16) & 127;
        int pos = atomicAdd(&cursor[d], 1);
        sorted[pos] = (unsigned short)(v & 0xffffu);
    }
    __syncthreads();
    for (int i = t; i < cnt; i += 256) csr[s0 + i] = sorted[i];
}

// ---------- quantum features: one wave per node, DPP reductions, fp16 z ----------
__global__ __launch_bounds__(256) void k_feat(const float* __restrict__ x,
        const float* __restrict__ dinv, const float4* __restrict__ cmat,
        __half* __restrict__ z){
    int wave = threadIdx.x >> 6;
    int lane = threadIdx.x & 63;
    int n = blockIdx.x*4 + wave;
    const float4 v = ((const float4*)(x + (size_t)n*256))[lane];
    float persq = v.x*v.x + v.y*v.y + v.z*v.z + v.w*v.w;

    float red[15];
    red[0] = persq;
    red[1] = v.x*v.x + v.y*v.y;        // S0 qubit6
    red[2] = v.x*v.z + v.y*v.w;        // X qubit6
    {   // j=0: xor mask 1 via DPP quad_perm
        float px = dpp_mov<DPP_XOR1>(v.x), py = dpp_mov<DPP_XOR1>(v.y);
        float pz = dpp_mov<DPP_XOR1>(v.z), pw = dpp_mov<DPP_XOR1>(v.w);
        red[3] = v.x*px + v.y*py + v.z*pz + v.w*pw;
        red[9] = (lane & 1) ? 0.f : persq;
    }
    {   // j=1: xor mask 2 via DPP quad_perm
        float px = dpp_mov<DPP_XOR2>(v.x), py = dpp_mov<DPP_XOR2>(v.y);
        float pz = dpp_mov<DPP_XOR2>(v.z), pw = dpp_mov<DPP_XOR2>(v.w);
        red[4] = v.x*px + v.y*py + v.z*pz + v.w*pw;
        red[10] = (lane & 2) ? 0.f : persq;
    }
    #pragma unroll
    for (int j = 2; j < 6; j++){
        float px = __shfl_xor(v.x, 1 << j), py = __shfl_xor(v.y, 1 << j);
        float pz = __shfl_xor(v.z, 1 << j), pw = __shfl_xor(v.w, 1 << j);
        red[3 + j] = v.x*px + v.y*py + v.z*pz + v.w*pw;
        red[9 + j] = ((lane >> j) & 1) ? 0.0f : persq;
    }
    float S[15];
    #pragma unroll
    for (int k = 0; k < 15; k++) S[k] = lane63(wave_sum_dpp(red[k]));

    if (lane < 28){
        float4 cm = cmat[lane];
        int ap = (int)cm.w;
        float S0a = (ap==6) ? S[1] :
                    (ap==0 ? S[14] : ap==1 ? S[13] : ap==2 ? S[12] :
                     ap==3 ? S[11] : ap==4 ? S[10] : S[9]);
        float Xa  = (ap==6) ? S[2] :
                    0.5f*(ap==0 ? S[8] : ap==1 ? S[7] : ap==2 ? S[6] :
                          ap==3 ? S[5] : ap==4 ? S[4] : S[3]);
        float feat = cm.x + (cm.y*S0a + cm.z*Xa) / S[0];
        z[(size_t)n*ZSTRIDE + lane] = __float2half(dinv[n] * feat);
    } else if (lane < 32){
        z[(size_t)n*ZSTRIDE + lane] = __float2half(0.f);   // zero pad (gather reads full row)
    }
}

// ---------- GCN aggregate + relu: 4 threads/node, fp16 rows, DPP combine ----------
__device__ inline void acc_pack(unsigned u, float& a, float& b){
    float2 f = __half22float2(__builtin_bit_cast(__half2, u));
    a += f.x; b += f.y;
}
__device__ inline void acc_row(const uint4* rp, float* acc /*32*/){
    uint4 w0 = rp[0], w1 = rp[1], w2 = rp[2], w3 = rp[3];
    acc_pack(w0.x, acc[0],  acc[1]);  acc_pack(w0.y, acc[2],  acc[3]);
    acc_pack(w0.z, acc[4],  acc[5]);  acc_pack(w0.w, acc[6],  acc[7]);
    acc_pack(w1.x, acc[8],  acc[9]);  acc_pack(w1.y, acc[10], acc[11]);
    acc_pack(w1.z, acc[12], acc[13]); acc_pack(w1.w, acc[14], acc[15]);
    acc_pack(w2.x, acc[16], acc[17]); acc_pack(w2.y, acc[18], acc[19]);
    acc_pack(w2.z, acc[20], acc[21]); acc_pack(w2.w, acc[22], acc[23]);
    acc_pack(w3.x, acc[24], acc[25]); acc_pack(w3.y, acc[26], acc[27]);
    acc_pack(w3.z, acc[28], acc[29]); acc_pack(w3.w, acc[30], acc[31]);
}

__global__ __launch_bounds__(256) void k_gather(const unsigned short* __restrict__ csr,
        const int* __restrict__ nodeOff, const __half* __restrict__ z,
        const float* __restrict__ dinv, float* __restrict__ out){
    int g = blockIdx.x*256 + threadIdx.x;
    int n = g >> 2, sub = g & 3;
    if (n >= N_NODES) return;
    int beg = nodeOff[n];
    int end = (n == N_NODES - 1) ? N_EDGES : nodeOff[n + 1];
    float acc[32];
    #pragma unroll
    for (int k = 0; k < 32; k++) acc[k] = 0.f;
    for (int i = beg + sub; i < end; i += 4){
        int src = csr[i];
        acc_row((const uint4*)(z + (size_t)src*ZSTRIDE), acc);
    }
    if (sub == 3) acc_row((const uint4*)(z + (size_t)n*ZSTRIDE), acc);  // self loop
    #pragma unroll
    for (int k = 0; k < 32; k++){
        acc[k] += dpp_mov<DPP_XOR1>(acc[k]);
        acc[k] += dpp_mov<DPP_XOR2>(acc[k]);
    }
    if (sub == 0){
        float dv = dinv[n];
        float4* o = (float4*)(out + (size_t)n*28);
        #pragma unroll
        for (int q = 0; q < 7; q++)
            o[q] = make_float4(fmaxf(acc[4*q+0]*dv, 0.f), fmaxf(acc[4*q+1]*dv, 0.f),
                               fmaxf(acc[4*q+2]*dv, 0.f), fmaxf(acc[4*q+3]*dv, 0.f));
    }
}

// ---------- Gram: 2x2 register tiling, 4 LDS reads per node per thread ----------
__global__ __launch_bounds__(256) void k_gram(const float* __restrict__ out, float* __restrict__ G){
    __shared__ float buf[64*28];
    int tid = threadIdx.x;
    bool val = tid < 196;
    int ti = val ? tid / 14 : 0, tj = val ? tid % 14 : 0;
    int i0 = 2*ti, j0 = 2*tj;
    float c00 = 0.f, c01 = 0.f, c10 = 0.f, c11 = 0.f;
    int nchunks = (N_NODES + 63) / 64;
    for (int ch = blockIdx.x; ch < nchunks; ch += gridDim.x){
        int base = ch * 64;
        int total = (N_NODES - base < 64 ? N_NODES - base : 64) * 28;
        __syncthreads();
        for (int t = tid; t < 64*28; t += 256)
            buf[t] = (t < total) ? out[(size_t)base*28 + t] : 0.f;
        __syncthreads();
        for (int nn = 0; nn < 64; nn++){
            const float* r = buf + nn*28;
            float a0 = r[i0], a1 = r[i0+1], b0 = r[j0], b1 = r[j0+1];
            c00 += a0*b0; c01 += a0*b1; c10 += a1*b0; c11 += a1*b1;
        }
    }
    if (val){
        atomicAdd(&G[(i0  )*28 + j0  ], c00);
        atomicAdd(&G[(i0  )*28 + j0+1], c01);
        atomicAdd(&G[(i0+1)*28 + j0  ], c10);
        atomicAdd(&G[(i0+1)*28 + j0+1], c11);
    }
}

// ---------- fused MLP: h = relu(G@W1^T + b1); out = sigmoid(h@W2^T + b2) ----------
__global__ __launch_bounds__(256) void k_mlp(const float* __restrict__ G,
        const float* __restrict__ W1, const float* __restrict__ b1,
        const float* __restrict__ W2, const float* __restrict__ b2,
        float* __restrict__ outp){
    __shared__ float part[256];
    __shared__ float h[128];
    int t = threadIdx.x;
    int j = t & 127, halfsel = t >> 7;
    const float* w = W1 + (size_t)j*784 + halfsel*392;
    const float* g = G + halfsel*392;
    float s = 0.f;
    for (int i = 0; i < 392; i++) s += g[i] * w[i];
    part[t] = s;
    __syncthreads();
    if (t < 128) h[t] = fmaxf(part[t] + part[t+128] + b1[t], 0.f) * W2[t];
    __syncthreads();
    for (int ofs = 64; ofs > 0; ofs >>= 1){
        if (t < ofs) h[t] += h[t + ofs];
        __syncthreads();
    }
    if (t == 0) outp[0] = 1.f / (1.f + expf(-(h[0] + b2[0])));
}

extern "C" void kernel_launch(void* const* d_in, const int* in_sizes, int n_in,
                              void* d_out, int out_size, void* d_ws, size_t ws_size,
                              hipStream_t stream){
    const float* x  = (const float*)d_in[0];
    const void*  ei = d_in[1];
    const float* qw = (const float*)d_in[2];
    const float* W1 = (const float*)d_in[3];
    const float* b1 = (const float*)d_in[4];
    const float* W2 = (const float*)d_in[5];
    const float* b2 = (const float*)d_in[6];
    float* outp = (float*)d_out;

    char* base = (char*)d_ws;
    __half*         z     = (__half*)base;         base += (size_t)N_NODES*ZSTRIDE*2;
    float*          ob    = (float*)base;          base += (size_t)N_NODES*28*4;
    unsigned*       pairs = (unsigned*)base;       base += (size_t)N_EDGES*4;
    unsigned short* csr   = (unsigned short*)base; base += (size_t)N_EDGES*2;
    int*            nodeOff = (int*)base;          base += (size_t)N_NODES*4;
    float*          dinv  = (float*)base;          base += (size_t)N_NODES*4;
    int*            chunkCnt    = (int*)base;      base += (size_t)NB_BUCKETS*NCHUNK*4;
    int*            rawCnt      = (int*)base;      base += (size_t)NCHUNK*NB_PAD*4;
    int*            bucketCnt   = (int*)base;      base += 2048;
    int*            bucketStart = (int*)base;      base += 2048;
    float4*         cmat  = (float4*)base;         base += 448;
    float*          G     = (float*)base;          base += 1024*4;
    int*            flag  = (int*)base;            base += 16;

    k_init<<<1, 64, 0, stream>>>(qw, ei, cmat, flag);
    k_part1<<<NCHUNK, 256, 0, stream>>>(ei, flag, chunkCnt, rawCnt, G);
    k_chunkscan<<<NB_BUCKETS, 256, 0, stream>>>(chunkCnt, bucketCnt);
    k_scanb<<<1, 256, 0, stream>>>(bucketCnt, bucketStart);
    k_part2<<<NCHUNK, 256, 0, stream>>>(ei, flag, chunkCnt, rawCnt, bucketStart, pairs);
    k_sort<<<NB_BUCKETS, 256, 0, stream>>>(pairs, bucketStart, csr, nodeOff, dinv);
    k_feat<<<N_NODES/4, 256, 0, stream>>>(x, dinv, cmat, z);
    k_gather<<<(N_NODES*4 + 255)/256, 256, 0, stream>>>(csr, nodeOff, z, dinv, ob);
    k_gram<<<196, 256, 0, stream>>>(ob, G);
    k_mlp<<<1, 256, 0, stream>>>(G, W1, b1, W2, b2, outp);
}